// Round 7
// baseline (391.091 us; speedup 1.0000x reference)
//
#include <hip/hip_runtime.h>
#include <math.h>

#define BB 48
#define LL 512
#define DD 192
#define HH 6
#define DKK 32
#define HID 768
#define ROWS (BB * LL)
#define BLD ((size_t)ROWS * DD)
#define SB2 0.25503531f                 // (1/sqrt(32)) * log2(e)
#define MASKED_X (-36.0f)               // exp2(-36) ~= 1.5e-11 (uniform floor)

typedef unsigned short ushort_t;
typedef unsigned int uint_t;
typedef __bf16 bf16x8 __attribute__((ext_vector_type(8)));
typedef float f32x4 __attribute__((ext_vector_type(4)));

union U4BF8 { uint4 u; bf16x8 b; };
union BFU { __bf16 h; ushort_t u; };

__device__ __forceinline__ ushort_t f2bf(float f) {
  union { float f; uint_t u; } v; v.f = f;
  uint_t r = v.u + 0x7fffu + ((v.u >> 16) & 1u);
  return (ushort_t)(r >> 16);
}
__device__ __forceinline__ ushort_t cvt_bf(float f) {
  BFU c; c.h = (__bf16)f; return c.u;
}

// Swizzled weight offset: fragment-major so a wave's dwordx4 load of one
// 16x32 (n x k) MFMA B-tile is lane-linear (fully coalesced 1KB/wave).
__device__ __forceinline__ int swz_w(int n, int k, int N) {
  return ((k >> 5) * (N >> 4) + (n >> 4)) * 512 +
         ((((k & 31) >> 3) << 4) + (n & 15)) * 8 + (k & 7);
}

// ---------------------------------------------------------------------------
__global__ __launch_bounds__(256) void pack_kernel(
    const float* __restrict__ wq, const float* __restrict__ wk,
    const float* __restrict__ wv, const float* __restrict__ wo,
    const float* __restrict__ w1, const float* __restrict__ w2,
    const float* __restrict__ bq, const float* __restrict__ bk,
    const float* __restrict__ bv,
    ushort_t* __restrict__ Wqkv, ushort_t* __restrict__ Wo,
    ushort_t* __restrict__ W1, ushort_t* __restrict__ W2,
    float* __restrict__ bqkv) {
  int i = blockIdx.x * 256 + threadIdx.x;
  if (i < 110592) {                       // Wqkv swizzled, N=576
    int n2 = i / 192, k = i - n2 * 192;
    int part = n2 / 192, n = n2 - part * 192;
    const float* src = part == 0 ? wq : (part == 1 ? wk : wv);
    Wqkv[swz_w(n2, k, 576)] = f2bf(src[k * 192 + n]);
  } else if (i < 147456) {                // Wo swizzled, N=192
    int j = i - 110592;
    int n = j / 192, k = j - n * 192;
    Wo[swz_w(n, k, 192)] = f2bf(wo[k * 192 + n]);
  } else if (i < 294912) {                // W1_t [768][192]
    int j = i - 147456;
    int n = j / 192, k = j - n * 192;
    W1[j] = f2bf(w1[k * 768 + n]);
  } else if (i < 442368) {                // W2_t [192][768]
    int j = i - 294912;
    int n = j / 768, k = j - n * 768;
    W2[j] = f2bf(w2[k * 192 + n]);
  } else if (i < 442944) {                // bqkv [576]
    int j = i - 442368;
    bqkv[j] = j < 192 ? bq[j] : (j < 384 ? bk[j - 192] : bv[j - 384]);
  }
}

// ---------------------------------------------------------------------------
// Fused pre-LN + QKV projection. Block = 32 rows x 576 cols, 256 threads.
// Q,K (cols 0..383) -> QK[2R][384] via LDS re-stage (full-line stores).
// V (cols 384..575) -> Vt[(side,b,h)*32+d][512] DIRECTLY from accumulators:
// each lane holds 4 consecutive k-rows at fixed d = a ready-made V^T pack.
// ---------------------------------------------------------------------------
__global__ __launch_bounds__(256) void qkv_ln_kernel(
    const float* __restrict__ xa, const float* __restrict__ xb,
    const int* __restrict__ va, const int* __restrict__ vb,
    const float* __restrict__ g_a, const float* __restrict__ b_a,
    const float* __restrict__ g_b, const float* __restrict__ b_b,
    const ushort_t* __restrict__ Wsw, const float* __restrict__ bias,
    ushort_t* __restrict__ QK, ushort_t* __restrict__ Vt) {
  constexpr int N = 576;
  constexpr int CSB = 392;               // Q,K staging stride (384+8)
  __shared__ ushort_t smem[32 * CSB];    // 25.1 KB; As (12.8 KB) overlays
  ushort_t* As = smem;

  int tid = threadIdx.x;
  int w = tid >> 6, lane = tid & 63, l15 = lane & 15, kq = lane >> 4;
  int row0 = blockIdx.x * 32;
  int side = row0 >= ROWS;
  int rb = row0 - side * ROWS;
  int batch = rb >> 9;
  int k0 = rb & 511;

  // --- phase 1: masked LN, x fp32 -> As bf16 ---
  {
    int row = tid >> 3, l8 = tid & 7;
    const float* xr = (side ? xb : xa) + (size_t)(rb + row) * DD + l8 * 24;
    float v[24];
    float s = 0.f;
#pragma unroll
    for (int j = 0; j < 6; ++j) {
      float4 q = *(const float4*)(xr + j * 4);
      v[j*4+0] = q.x; v[j*4+1] = q.y; v[j*4+2] = q.z; v[j*4+3] = q.w;
      s += q.x + q.y + q.z + q.w;
    }
    s += __shfl_xor(s, 1); s += __shfl_xor(s, 2); s += __shfl_xor(s, 4);
    float mu = s * (1.0f / 192.0f);
    float ss = 0.f;
#pragma unroll
    for (int j = 0; j < 24; ++j) { float d = v[j] - mu; ss += d * d; }
    ss += __shfl_xor(ss, 1); ss += __shfl_xor(ss, 2); ss += __shfl_xor(ss, 4);
    float inv = rsqrtf(ss * (1.0f / 192.0f) + 1e-5f);
    int vld = (side ? vb : va)[rb + row];
    const float* g = side ? g_b : g_a;
    const float* be = side ? b_b : b_a;
    ushort_t ob[24];
#pragma unroll
    for (int j = 0; j < 24; ++j) {
      int col = l8 * 24 + j;
      float r = vld ? (v[j] - mu) * inv * g[col] + be[col] : v[j];
      ob[j] = f2bf(r);
    }
#pragma unroll
    for (int j = 0; j < 3; ++j)
      *(uint4*)(&As[row * 200 + l8 * 24 + j * 8]) = *(const uint4*)(&ob[j * 8]);
  }
  __syncthreads();

  // --- phase 2: GEMM (full N=576) ---
  f32x4 acc[2][9];
#pragma unroll
  for (int qs = 0; qs < 2; ++qs)
#pragma unroll
    for (int nt = 0; nt < 9; ++nt) acc[qs][nt] = (f32x4){0.f, 0.f, 0.f, 0.f};

#pragma unroll 1
  for (int kk = 0; kk < 6; ++kk) {
    bf16x8 af[2];
#pragma unroll
    for (int qs = 0; qs < 2; ++qs)
      af[qs] = *(const bf16x8*)(&As[(qs * 16 + l15) * 200 + kk * 32 + kq * 8]);
    const ushort_t* wp =
        Wsw + ((size_t)(kk * (N >> 4) + w * 9) << 9) + lane * 8;
#pragma unroll
    for (int nt = 0; nt < 9; ++nt) {
      U4BF8 wf;
      wf.u = *(const uint4*)(wp + (nt << 9));
#pragma unroll
      for (int qs = 0; qs < 2; ++qs)
        acc[qs][nt] = __builtin_amdgcn_mfma_f32_16x16x32_bf16(
            af[qs], wf.b, acc[qs][nt], 0, 0, 0);
    }
  }
  __syncthreads();  // As dead; smem reused for Q,K staging

  // --- phase 3: epilogue ---
  ushort_t* Cs = smem;
#pragma unroll
  for (int nt = 0; nt < 9; ++nt) {
    int t = w * 9 + nt;                  // 0..35 column tile
    int col = t * 16 + l15;
    float bb = bias[col];
    if (t < 24) {                        // Q,K -> LDS staging
#pragma unroll
      for (int qs = 0; qs < 2; ++qs)
#pragma unroll
        for (int r = 0; r < 4; ++r)
          Cs[(qs * 16 + kq * 4 + r) * CSB + col] = f2bf(acc[qs][nt][r] + bb);
    } else {                             // V -> Vt direct (bf16x4 packs)
      int vcol = col - 384;
      int h = vcol >> 5, d = vcol & 31;
      size_t vbase = ((size_t)((side * BB + batch) * HH + h) * 32 + d) * 512;
#pragma unroll
      for (int qs = 0; qs < 2; ++qs) {
        ushort_t pk[4];
#pragma unroll
        for (int r = 0; r < 4; ++r) pk[r] = f2bf(acc[qs][nt][r] + bb);
        *(uint2*)(Vt + vbase + k0 + qs * 16 + kq * 4) = *(const uint2*)(&pk[0]);
      }
    }
  }
  __syncthreads();
  // linear full-line store of Q,K rows (32 x 384 bf16)
  constexpr int UPR = 48;                // uint4 per row
#pragma unroll
  for (int i = 0; i < (32 * UPR) / 256; ++i) {
    int idx = tid + i * 256;
    int r = idx / UPR, u = idx - r * UPR;
    *(uint4*)(QK + (size_t)row0 * 384 + idx * 8) =
        *(const uint4*)(&Cs[r * CSB + u * 8]);
  }
}

// ---------------------------------------------------------------------------
// Fused O-projection + residual + LN-chain. Block = 32 rows x 192 cols.
// ---------------------------------------------------------------------------
__global__ __launch_bounds__(256) void oproj_ln_kernel(
    const ushort_t* __restrict__ A, const ushort_t* __restrict__ Wsw,
    const float* __restrict__ bias,
    const float* __restrict__ xa, const float* __restrict__ xb,
    const int* __restrict__ va, const int* __restrict__ vb,
    const float* __restrict__ g_oa, const float* __restrict__ b_oa,
    const float* __restrict__ g_ob, const float* __restrict__ b_ob,
    const float* __restrict__ g_f, const float* __restrict__ b_f,
    float* __restrict__ outf, ushort_t* __restrict__ outb) {
  __shared__ float smemf[32 * 196];      // 25 KB; As (12.8 KB) overlays
  ushort_t* As = (ushort_t*)smemf;

  int tid = threadIdx.x;
  int w = tid >> 6, lane = tid & 63, l15 = lane & 15, kq = lane >> 4;
  int row0 = blockIdx.x * 32;
  int side = row0 >= ROWS;
  int rb = row0 - side * ROWS;

  // stage A (attO) 32x192 bf16
  {
    const ushort_t* ap = A + (size_t)row0 * DD;
#pragma unroll
    for (int i = 0; i < 3; ++i) {
      int idx = tid + i * 256;
      int r = idx / 24, c = (idx - r * 24) * 8;
      *(uint4*)(&As[r * 200 + c]) = *(const uint4*)(ap + idx * 8);
    }
  }
  __syncthreads();

  f32x4 acc[2][3];
#pragma unroll
  for (int qs = 0; qs < 2; ++qs)
#pragma unroll
    for (int nt = 0; nt < 3; ++nt) acc[qs][nt] = (f32x4){0.f, 0.f, 0.f, 0.f};

#pragma unroll 1
  for (int kk = 0; kk < 6; ++kk) {
    bf16x8 af[2];
#pragma unroll
    for (int qs = 0; qs < 2; ++qs)
      af[qs] = *(const bf16x8*)(&As[(qs * 16 + l15) * 200 + kk * 32 + kq * 8]);
    const ushort_t* wp =
        Wsw + ((size_t)(kk * (192 >> 4) + w * 3) << 9) + lane * 8;
#pragma unroll
    for (int nt = 0; nt < 3; ++nt) {
      U4BF8 wf;
      wf.u = *(const uint4*)(wp + (nt << 9));
#pragma unroll
      for (int qs = 0; qs < 2; ++qs)
        acc[qs][nt] = __builtin_amdgcn_mfma_f32_16x16x32_bf16(
            af[qs], wf.b, acc[qs][nt], 0, 0, 0);
    }
  }
  __syncthreads();  // As dead

  // stage C + bias -> Cs fp32
  float* Cs = smemf;
#pragma unroll
  for (int nt = 0; nt < 3; ++nt) {
    int col = (w * 3 + nt) * 16 + l15;
    float bb = bias[col];
#pragma unroll
    for (int qs = 0; qs < 2; ++qs)
#pragma unroll
      for (int r = 0; r < 4; ++r)
        Cs[(qs * 16 + kq * 4 + r) * 196 + col] = acc[qs][nt][r] + bb;
  }
  __syncthreads();

  // row phase: 8 threads/row, interleaved cols (col = j*32 + l8*4)
  int row = tid >> 3, l8 = tid & 7;
  int grow = row0 + row;
  const float* xrow = (side ? xb : xa) + (size_t)(rb + row) * DD;
  const float* crow = &Cs[row * 196];
  float v[24];
  float s = 0.f;
#pragma unroll
  for (int j = 0; j < 6; ++j) {
    int col = j * 32 + l8 * 4;
    float4 q = *(const float4*)(xrow + col);
    v[j*4+0] = crow[col+0] + q.x; v[j*4+1] = crow[col+1] + q.y;
    v[j*4+2] = crow[col+2] + q.z; v[j*4+3] = crow[col+3] + q.w;
    s += v[j*4+0] + v[j*4+1] + v[j*4+2] + v[j*4+3];
  }
  s += __shfl_xor(s, 1); s += __shfl_xor(s, 2); s += __shfl_xor(s, 4);
  float mu = s * (1.0f / 192.0f);
  float ss = 0.f;
#pragma unroll
  for (int j = 0; j < 24; ++j) { float d = v[j] - mu; ss += d * d; }
  ss += __shfl_xor(ss, 1); ss += __shfl_xor(ss, 2); ss += __shfl_xor(ss, 4);
  float inv = rsqrtf(ss * (1.0f / 192.0f) + 1e-5f);
  int vld = (side ? vb : va)[rb + row];
  const float* g1 = side ? g_ob : g_oa;
  const float* b1 = side ? b_ob : b_oa;
  float y[24];
#pragma unroll
  for (int j = 0; j < 6; ++j) {
#pragma unroll
    for (int e = 0; e < 4; ++e) {
      int col = j * 32 + l8 * 4 + e;
      float vv = v[j * 4 + e];
      y[j * 4 + e] = vld ? (vv - mu) * inv * g1[col] + b1[col] : vv;
    }
  }
  float* orow = outf + (size_t)grow * DD;
#pragma unroll
  for (int j = 0; j < 6; ++j) {
    float4 q = {y[j*4+0], y[j*4+1], y[j*4+2], y[j*4+3]};
    *(float4*)(orow + j * 32 + l8 * 4) = q;
  }
  // LN2 -> bf16
  float s2 = 0.f;
#pragma unroll
  for (int j = 0; j < 24; ++j) s2 += y[j];
  s2 += __shfl_xor(s2, 1); s2 += __shfl_xor(s2, 2); s2 += __shfl_xor(s2, 4);
  float mu2 = s2 * (1.0f / 192.0f);
  float ss2 = 0.f;
#pragma unroll
  for (int j = 0; j < 24; ++j) { float e = y[j] - mu2; ss2 += e * e; }
  ss2 += __shfl_xor(ss2, 1); ss2 += __shfl_xor(ss2, 2); ss2 += __shfl_xor(ss2, 4);
  float inv2 = rsqrtf(ss2 * (1.0f / 192.0f) + 1e-5f);
  ushort_t* obrow = outb + (size_t)grow * DD;
#pragma unroll
  for (int j = 0; j < 6; ++j) {
    ushort_t zb[4];
#pragma unroll
    for (int e = 0; e < 4; ++e) {
      int col = j * 32 + l8 * 4 + e;
      float z = vld ? (y[j*4+e] - mu2) * inv2 * g_f[col] + b_f[col] : y[j*4+e];
      zb[e] = f2bf(z);
    }
    *(uint2*)(obrow + j * 32 + l8 * 4) = *(const uint2*)(&zb[0]);
  }
}

// ---------------------------------------------------------------------------
// Fused FFN + final residual + LN. 256 threads (4 waves), 64 rows/block.
// ---------------------------------------------------------------------------
__global__ __launch_bounds__(256, 3) void ffn_fused_kernel(
    const ushort_t* __restrict__ A, const ushort_t* __restrict__ W1t,
    const float* __restrict__ bias1, const ushort_t* __restrict__ W2t,
    const float* __restrict__ bias2,
    const int* __restrict__ va, const int* __restrict__ vb,
    const float* __restrict__ g_f, const float* __restrict__ b_f,
    float* __restrict__ outf) {
  __shared__ float smemf[64 * 196];      // 50.2 KB epilogue Cs; overlays:
  ushort_t* As = (ushort_t*)smemf;       //   As 64*200 us (25.6 KB)
  ushort_t* Hs = As + 64 * 200;          //   Hs 2*64*72 us (18.4 KB)

  int tid = threadIdx.x;
  int w = tid >> 6;
  int lane = tid & 63;
  int l15 = lane & 15;
  int kq = lane >> 4;
  int row0 = blockIdx.x * 64;
  int side = row0 >= ROWS;
  int rb0 = row0 - side * ROWS;

  // stage A: 64 rows x 24 uint4 = 1536 / 256 threads = 6 each
#pragma unroll
  for (int i = 0; i < 6; ++i) {
    int idx = tid + i * 256;
    int r = idx / 24, c = (idx % 24) * 8;
    *(uint4*)(&As[r * 200 + c]) = *(const uint4*)(A + (size_t)(row0 + r) * DD + c);
  }

  const ushort_t* w1p = W1t + (size_t)(w * 16 + l15) * DD + kq * 8;
  const ushort_t* w2p = W2t + (size_t)(w * 48 + l15) * HID + kq * 8;

  U4BF8 w1f[6], w1n[6], w2f[6];
#pragma unroll
  for (int kk = 0; kk < 6; ++kk)
    w1f[kk].u = *(const uint4*)(w1p + kk * 32);  // hc = 0

  f32x4 Cacc[4][3];
#pragma unroll
  for (int qs = 0; qs < 4; ++qs)
#pragma unroll
    for (int nt = 0; nt < 3; ++nt) Cacc[qs][nt] = (f32x4){0.f, 0.f, 0.f, 0.f};

  __syncthreads();   // As ready

  for (int hc = 0; hc < 12; ++hc) {
#pragma unroll
    for (int kk2 = 0; kk2 < 2; ++kk2)
#pragma unroll
      for (int nt = 0; nt < 3; ++nt)
        w2f[kk2 * 3 + nt].u =
            *(const uint4*)(w2p + (size_t)(nt * 16) * HID + hc * 64 + kk2 * 32);

    f32x4 Hacc[4];
#pragma unroll
    for (int qs = 0; qs < 4; ++qs) Hacc[qs] = (f32x4){0.f, 0.f, 0.f, 0.f};
#pragma unroll
    for (int kk = 0; kk < 6; ++kk) {
#pragma unroll
      for (int qs = 0; qs < 4; ++qs) {
        bf16x8 af = *(const bf16x8*)(&As[(qs * 16 + l15) * 200 + kk * 32 + kq * 8]);
        Hacc[qs] = __builtin_amdgcn_mfma_f32_16x16x32_bf16(
            af, w1f[kk].b, Hacc[qs], 0, 0, 0);
      }
    }

    if (hc < 11) {
#pragma unroll
      for (int kk = 0; kk < 6; ++kk)
        w1n[kk].u = *(const uint4*)(w1p + (size_t)(hc + 1) * 64 * DD + kk * 32);
    }

    {
      float bb = bias1[hc * 64 + w * 16 + l15];
      ushort_t* hb = &Hs[(hc & 1) * 4608];
#pragma unroll
      for (int qs = 0; qs < 4; ++qs)
#pragma unroll
        for (int r = 0; r < 4; ++r) {
          float x = Hacc[qs][r] + bb;
          x = 0.5f * x * (1.0f + erff(x * 0.70710678118654752f));
          hb[(qs * 16 + kq * 4 + r) * 72 + w * 16 + l15] = f2bf(x);
        }
    }
    __syncthreads();

#pragma unroll
    for (int kk2 = 0; kk2 < 2; ++kk2) {
      bf16x8 hf[4];
#pragma unroll
      for (int qs = 0; qs < 4; ++qs)
        hf[qs] = *(const bf16x8*)(&Hs[(hc & 1) * 4608 +
                                      (qs * 16 + l15) * 72 + kk2 * 32 + kq * 8]);
#pragma unroll
      for (int nt = 0; nt < 3; ++nt)
#pragma unroll
        for (int qs = 0; qs < 4; ++qs)
          Cacc[qs][nt] = __builtin_amdgcn_mfma_f32_16x16x32_bf16(
              hf[qs], w2f[kk2 * 3 + nt].b, Cacc[qs][nt], 0, 0, 0);
    }

#pragma unroll
    for (int kk = 0; kk < 6; ++kk) w1f[kk] = w1n[kk];
  }
  __syncthreads();   // As/Hs dead; smemf becomes epilogue Cs

  // epilogue: stage C + bias2, then per-row residual + masked LN
  float* Cs = smemf;
#pragma unroll
  for (int qs = 0; qs < 4; ++qs)
#pragma unroll
    for (int nt = 0; nt < 3; ++nt) {
      int col = w * 48 + nt * 16 + l15;
      float bb = bias2[col];
#pragma unroll
      for (int r = 0; r < 4; ++r)
        Cs[(qs * 16 + kq * 4 + r) * 196 + col] = Cacc[qs][nt][r] + bb;
    }
  __syncthreads();

  // 4 threads/row, interleaved cols (col = j*16 + l4*4)
  int row = tid >> 2, l4 = tid & 3;
  int grow = row0 + row;
  float* orow = outf + (size_t)grow * DD;
  const float* crow = &Cs[row * 196];
  float v[48];
  float s = 0.f;
#pragma unroll
  for (int j = 0; j < 12; ++j) {
    int col = j * 16 + l4 * 4;
    float4 q = *(const float4*)(orow + col);   // residual (in-place read)
    v[j*4+0] = crow[col+0] + q.x; v[j*4+1] = crow[col+1] + q.y;
    v[j*4+2] = crow[col+2] + q.z; v[j*4+3] = crow[col+3] + q.w;
    s += v[j*4+0] + v[j*4+1] + v[j*4+2] + v[j*4+3];
  }
  s += __shfl_xor(s, 1); s += __shfl_xor(s, 2);
  float mu = s * (1.0f / 192.0f);
  float ss = 0.f;
#pragma unroll
  for (int j = 0; j < 48; ++j) { float d = v[j] - mu; ss += d * d; }
  ss += __shfl_xor(ss, 1); ss += __shfl_xor(ss, 2);
  float inv = rsqrtf(ss * (1.0f / 192.0f) + 1e-5f);
  int vld = (side ? vb : va)[rb0 + row];
#pragma unroll
  for (int j = 0; j < 12; ++j) {
    int col = j * 16 + l4 * 4;
    float4 q;
#pragma unroll
    for (int e = 0; e < 4; ++e) {
      float vv = v[j * 4 + e];
      ((float*)&q)[e] = vld ? (vv - mu) * inv * g_f[col + e] + b_f[col + e] : vv;
    }
    *(float4*)(orow + col) = q;
  }
}

// ---------------------------------------------------------------------------
// MFMA flash attention v5: ZERO barriers, ZERO V staging. V is pre-transposed
// (Vt[(side,b,h)*32+d][512]) by the QKV kernel, so PV B-fragments load
// straight from global (16B/lane contiguous, L2-hot 32KB per head).
// Only wave-private P LDS remains. 4 fully independent waves per block.
// ---------------------------------------------------------------------------
__global__ __launch_bounds__(256) void attn_mfma_kernel(
    const ushort_t* __restrict__ QK, const ushort_t* __restrict__ Vt,
    const int* __restrict__ valid_a, const int* __restrict__ valid_b,
    ushort_t* __restrict__ out) {
  int i = blockIdx.x;
  int gid = ((i >> 5) << 3) | (i & 7);
  int qt = (i >> 3) & 3;
  int side = gid >= BB * HH;
  int grem = side ? gid - BB * HH : gid;
  int h = grem % HH;
  int batch = grem / HH;
  int tid = threadIdx.x;
  int w = tid >> 6;
  int lane = tid & 63;
  int l15 = lane & 15;
  int kq = lane >> 4;

  const int* validq = side ? valid_b : valid_a;
  const int* validk = side ? valid_a : valid_b;
  size_t qrow0  = (size_t)side * ROWS + (size_t)batch * LL;
  size_t kvrow0 = (size_t)(1 - side) * ROWS + (size_t)batch * LL;
  const ushort_t* vtp =
      Vt + ((size_t)(((1 - side) * BB + batch) * HH + h) * 32) * 512;

  __shared__ ushort_t Ps[4][32 * 72];

  int qbase = qt * 128 + w * 32;

  U4BF8 qfrag[2];
#pragma unroll
  for (int qs = 0; qs < 2; ++qs)
    qfrag[qs].u = *(const uint4*)(QK + (qrow0 + qbase + qs * 16 + l15) * 384 +
                                  h * DKK + kq * 8);

  // per-(qs,r) fma coefficients: sqf = vq ? SB2 : 0, mq = vq ? 0 : -36
  float sqf[2][4], mq[2][4];
#pragma unroll
  for (int qs = 0; qs < 2; ++qs)
#pragma unroll
    for (int r = 0; r < 4; ++r) {
      int vq = validq[batch * LL + qbase + qs * 16 + kq * 4 + r];
      sqf[qs][r] = vq ? SB2 : 0.0f;
      mq[qs][r]  = vq ? 0.0f : MASKED_X;
    }

  float lsum[2][4];
  f32x4 Oacc[2][2];
#pragma unroll
  for (int qs = 0; qs < 2; ++qs) {
#pragma unroll
    for (int r = 0; r < 4; ++r) lsum[qs][r] = 0.0f;
#pragma unroll
    for (int ds = 0; ds < 2; ++ds) Oacc[qs][ds] = (f32x4){0.f, 0.f, 0.f, 0.f};
  }

  for (int c = 0; c < LL; c += 64) {
    f32x4 S[2][4];
    float mkb[4];
#pragma unroll
    for (int ks = 0; ks < 4; ++ks) {
      U4BF8 kf;
      kf.u = *(const uint4*)(QK + (kvrow0 + c + ks * 16 + l15) * 384 +
                             192 + h * DKK + kq * 8);
      mkb[ks] = validk[batch * LL + c + ks * 16 + l15] ? 0.0f : MASKED_X;
#pragma unroll
      for (int qs = 0; qs < 2; ++qs) {
        f32x4 z = (f32x4){0.f, 0.f, 0.f, 0.f};
        S[qs][ks] = __builtin_amdgcn_mfma_f32_16x16x32_bf16(
            qfrag[qs].b, kf.b, z, 0, 0, 0);
      }
    }

    // p = exp2(fma(S, sqf, min(mq, mkb)))
#pragma unroll
    for (int qs = 0; qs < 2; ++qs)
#pragma unroll
      for (int ks = 0; ks < 4; ++ks)
#pragma unroll
        for (int r = 0; r < 4; ++r) {
          float xs = fmaf(S[qs][ks][r], sqf[qs][r], fminf(mq[qs][r], mkb[ks]));
          float p = __builtin_amdgcn_exp2f(xs);
          lsum[qs][r] += p;
          Ps[w][(qs * 16 + kq * 4 + r) * 72 + ks * 16 + l15] = cvt_bf(p);
        }

    // PV: V^T fragments straight from global (L2-hot)
#pragma unroll
    for (int kh = 0; kh < 2; ++kh) {
      bf16x8 pf[2], vf[2];
#pragma unroll
      for (int qs = 0; qs < 2; ++qs)
        pf[qs] = *(const bf16x8*)(&Ps[w][(qs * 16 + l15) * 72 + kh * 32 + kq * 8]);
#pragma unroll
      for (int ds = 0; ds < 2; ++ds)
        vf[ds] = *(const bf16x8*)(vtp + (size_t)(ds * 16 + l15) * 512 +
                                  c + kh * 32 + kq * 8);
#pragma unroll
      for (int qs = 0; qs < 2; ++qs)
#pragma unroll
        for (int ds = 0; ds < 2; ++ds)
          Oacc[qs][ds] = __builtin_amdgcn_mfma_f32_16x16x32_bf16(
              pf[qs], vf[ds], Oacc[qs][ds], 0, 0, 0);
    }
  }

#pragma unroll
  for (int qs = 0; qs < 2; ++qs)
#pragma unroll
    for (int r = 0; r < 4; ++r) {
      float sm = lsum[qs][r];
#pragma unroll
      for (int off = 1; off < 16; off <<= 1) sm += __shfl_xor(sm, off);
      lsum[qs][r] = sm;
    }

#pragma unroll
  for (int qs = 0; qs < 2; ++qs)
#pragma unroll
    for (int ds = 0; ds < 2; ++ds)
#pragma unroll
      for (int r = 0; r < 4; ++r) {
        int q = qbase + qs * 16 + kq * 4 + r;
        out[(qrow0 + q) * DD + h * DKK + ds * 16 + l15] =
            f2bf(Oacc[qs][ds][r] / lsum[qs][r]);
      }
}

// ---------------------------------------------------------------------------
extern "C" void kernel_launch(void* const* d_in, const int* in_sizes, int n_in,
                              void* d_out, int out_size, void* d_ws, size_t ws_size,
                              hipStream_t stream) {
  const float* x_a = (const float*)d_in[0];
  const float* x_b = (const float*)d_in[1];
  const int* valid_a = (const int*)d_in[2];
  const int* valid_b = (const int*)d_in[3];
  const float* ln_a_g = (const float*)d_in[4];
  const float* ln_a_b = (const float*)d_in[5];
  const float* ln_b_g = (const float*)d_in[6];
  const float* ln_b_b = (const float*)d_in[7];
  const float* ln_oa_g = (const float*)d_in[8];
  const float* ln_oa_b = (const float*)d_in[9];
  const float* ln_ob_g = (const float*)d_in[10];
  const float* ln_ob_b = (const float*)d_in[11];
  const float* wq = (const float*)d_in[12];
  const float* bq = (const float*)d_in[13];
  const float* wk = (const float*)d_in[14];
  const float* bk = (const float*)d_in[15];
  const float* wv = (const float*)d_in[16];
  const float* bv = (const float*)d_in[17];
  const float* wo = (const float*)d_in[18];
  const float* bo = (const float*)d_in[19];
  const float* fln_g = (const float*)d_in[20];
  const float* fln_b = (const float*)d_in[21];
  const float* flno_g = (const float*)d_in[22];
  const float* flno_b = (const float*)d_in[23];
  const float* w1 = (const float*)d_in[24];
  const float* b1 = (const float*)d_in[25];
  const float* w2 = (const float*)d_in[26];
  const float* b2 = (const float*)d_in[27];

  // Workspace: weights [0, 887040); lnFull/attO bf16 [2R,192] at 887040;
  // QK bf16 [2R,384] at 19761408 (ends 57510144);
  // Vt bf16 [2*BB*HH*32][512] at 57510144 (ends 76384512).
  char* wsb = (char*)d_ws;
  ushort_t* Wqkv = (ushort_t*)wsb;
  ushort_t* Wo_t = Wqkv + 110592;
  ushort_t* W1_t = Wo_t + 36864;
  ushort_t* W2_t = W1_t + 147456;
  float*    bqkv = (float*)(W2_t + 147456);
  ushort_t* lnFull = (ushort_t*)(wsb + 887040);
  ushort_t* attO   = lnFull;
  ushort_t* QK = (ushort_t*)(wsb + 19761408);
  ushort_t* Vt = (ushort_t*)(wsb + 57510144);

  float* out_a = (float*)d_out;   // [2R,192] fp32 contiguous

  dim3 b256(256);
  dim3 gGemm(2 * ROWS / 32);                    // 1536 row-blocks
  dim3 gAttn(BB * HH * 4 * 2);                  // 2304
  dim3 gFFN(2 * ROWS / 64);                     // 768

  hipLaunchKernelGGL(pack_kernel, dim3(1731), b256, 0, stream,
                     wq, wk, wv, wo, w1, w2, bq, bk, bv,
                     Wqkv, Wo_t, W1_t, W2_t, bqkv);

  // 1+2. fused pre-LN + QKV projection; V written pre-transposed
  hipLaunchKernelGGL(qkv_ln_kernel, gGemm, b256, 0, stream,
                     x_a, x_b, valid_a, valid_b,
                     ln_a_g, ln_a_b, ln_b_g, ln_b_b,
                     Wqkv, bqkv, QK, Vt);

  // 3. attention, both sides (no barriers, no V staging)
  hipLaunchKernelGGL(attn_mfma_kernel, gAttn, b256, 0, stream,
                     QK, Vt, valid_a, valid_b, attO);

  // 4+5+6. fused O-proj + residual-LN -> d_out, FFN pre-LN -> lnFull bf16
  hipLaunchKernelGGL(oproj_ln_kernel, gGemm, b256, 0, stream,
                     attO, Wo_t, bo, x_a, x_b, valid_a, valid_b,
                     ln_oa_g, ln_oa_b, ln_ob_g, ln_ob_b, fln_g, fln_b,
                     out_a, lnFull);

  // 7+8. fused FFN + final residual + LN -> d_out (in place)
  hipLaunchKernelGGL(ffn_fused_kernel, gFFN, b256, 0, stream,
                     lnFull, W1_t, b1, W2_t, b2, valid_a, valid_b,
                     flno_g, flno_b, out_a);
}

// Round 8
// 390.582 us; speedup vs baseline: 1.0013x; 1.0013x over previous
//
#include <hip/hip_runtime.h>
#include <math.h>

#define BB 48
#define LL 512
#define DD 192
#define HH 6
#define DKK 32
#define HID 768
#define ROWS (BB * LL)
#define BLD ((size_t)ROWS * DD)
#define SB2 0.25503531f                 // (1/sqrt(32)) * log2(e)
#define MASKED_X (-36.0f)               // exp2(-36) ~= 1.5e-11 (uniform floor)

typedef unsigned short ushort_t;
typedef unsigned int uint_t;
typedef __bf16 bf16x8 __attribute__((ext_vector_type(8)));
typedef float f32x4 __attribute__((ext_vector_type(4)));

union U4BF8 { uint4 u; bf16x8 b; };
union BFU { __bf16 h; ushort_t u; };

__device__ __forceinline__ ushort_t f2bf(float f) {
  union { float f; uint_t u; } v; v.f = f;
  uint_t r = v.u + 0x7fffu + ((v.u >> 16) & 1u);
  return (ushort_t)(r >> 16);
}
__device__ __forceinline__ ushort_t cvt_bf(float f) {
  BFU c; c.h = (__bf16)f; return c.u;
}
// HW packed f32x2 -> bf16x2 (1 VALU op)
__device__ __forceinline__ uint_t cvtpk(float lo, float hi) {
  uint_t d;
  asm("v_cvt_pk_bf16_f32 %0, %1, %2" : "=v"(d) : "v"(lo), "v"(hi));
  return d;
}

// Swizzled weight offset: fragment-major so a wave's dwordx4 load of one
// 16x32 (n x k) MFMA B-tile is lane-linear (fully coalesced 1KB/wave).
__device__ __forceinline__ int swz_w(int n, int k, int N) {
  return ((k >> 5) * (N >> 4) + (n >> 4)) * 512 +
         ((((k & 31) >> 3) << 4) + (n & 15)) * 8 + (k & 7);
}

// ---------------------------------------------------------------------------
__global__ __launch_bounds__(256) void pack_kernel(
    const float* __restrict__ wq, const float* __restrict__ wk,
    const float* __restrict__ wv, const float* __restrict__ wo,
    const float* __restrict__ w1, const float* __restrict__ w2,
    const float* __restrict__ bq, const float* __restrict__ bk,
    const float* __restrict__ bv,
    ushort_t* __restrict__ Wqkv, ushort_t* __restrict__ Wo,
    ushort_t* __restrict__ W1, ushort_t* __restrict__ W2,
    float* __restrict__ bqkv) {
  int i = blockIdx.x * 256 + threadIdx.x;
  if (i < 110592) {                       // Wqkv swizzled, N=576
    int n2 = i / 192, k = i - n2 * 192;
    int part = n2 / 192, n = n2 - part * 192;
    const float* src = part == 0 ? wq : (part == 1 ? wk : wv);
    Wqkv[swz_w(n2, k, 576)] = f2bf(src[k * 192 + n]);
  } else if (i < 147456) {                // Wo swizzled, N=192
    int j = i - 110592;
    int n = j / 192, k = j - n * 192;
    Wo[swz_w(n, k, 192)] = f2bf(wo[k * 192 + n]);
  } else if (i < 294912) {                // W1_t [768][192]
    int j = i - 147456;
    int n = j / 192, k = j - n * 192;
    W1[j] = f2bf(w1[k * 768 + n]);
  } else if (i < 442368) {                // W2_t [192][768]
    int j = i - 294912;
    int n = j / 768, k = j - n * 768;
    W2[j] = f2bf(w2[k * 192 + n]);
  } else if (i < 442944) {                // bqkv [576]
    int j = i - 442368;
    bqkv[j] = j < 192 ? bq[j] : (j < 384 ? bk[j - 192] : bv[j - 384]);
  }
}

// ---------------------------------------------------------------------------
// Fused pre-LN + QKV projection. Block = 32 rows x 576 cols, 256 threads.
// Q,K -> QK[2R][384]; V -> Vt[(side,b,h)*32+d][512] directly from acc.
// ---------------------------------------------------------------------------
__global__ __launch_bounds__(256) void qkv_ln_kernel(
    const float* __restrict__ xa, const float* __restrict__ xb,
    const int* __restrict__ va, const int* __restrict__ vb,
    const float* __restrict__ g_a, const float* __restrict__ b_a,
    const float* __restrict__ g_b, const float* __restrict__ b_b,
    const ushort_t* __restrict__ Wsw, const float* __restrict__ bias,
    ushort_t* __restrict__ QK, ushort_t* __restrict__ Vt) {
  constexpr int N = 576;
  constexpr int CSB = 392;               // Q,K staging stride (384+8)
  __shared__ ushort_t smem[32 * CSB];    // 25.1 KB; As (12.8 KB) overlays
  ushort_t* As = smem;

  int tid = threadIdx.x;
  int w = tid >> 6, lane = tid & 63, l15 = lane & 15, kq = lane >> 4;
  int row0 = blockIdx.x * 32;
  int side = row0 >= ROWS;
  int rb = row0 - side * ROWS;
  int batch = rb >> 9;
  int k0 = rb & 511;

  // --- phase 1: masked LN, x fp32 -> As bf16 ---
  {
    int row = tid >> 3, l8 = tid & 7;
    const float* xr = (side ? xb : xa) + (size_t)(rb + row) * DD + l8 * 24;
    float v[24];
    float s = 0.f;
#pragma unroll
    for (int j = 0; j < 6; ++j) {
      float4 q = *(const float4*)(xr + j * 4);
      v[j*4+0] = q.x; v[j*4+1] = q.y; v[j*4+2] = q.z; v[j*4+3] = q.w;
      s += q.x + q.y + q.z + q.w;
    }
    s += __shfl_xor(s, 1); s += __shfl_xor(s, 2); s += __shfl_xor(s, 4);
    float mu = s * (1.0f / 192.0f);
    float ss = 0.f;
#pragma unroll
    for (int j = 0; j < 24; ++j) { float d = v[j] - mu; ss += d * d; }
    ss += __shfl_xor(ss, 1); ss += __shfl_xor(ss, 2); ss += __shfl_xor(ss, 4);
    float inv = rsqrtf(ss * (1.0f / 192.0f) + 1e-5f);
    int vld = (side ? vb : va)[rb + row];
    const float* g = side ? g_b : g_a;
    const float* be = side ? b_b : b_a;
    ushort_t ob[24];
#pragma unroll
    for (int j = 0; j < 24; ++j) {
      int col = l8 * 24 + j;
      float r = vld ? (v[j] - mu) * inv * g[col] + be[col] : v[j];
      ob[j] = f2bf(r);
    }
#pragma unroll
    for (int j = 0; j < 3; ++j)
      *(uint4*)(&As[row * 200 + l8 * 24 + j * 8]) = *(const uint4*)(&ob[j * 8]);
  }
  __syncthreads();

  // --- phase 2: GEMM (full N=576) ---
  f32x4 acc[2][9];
#pragma unroll
  for (int qs = 0; qs < 2; ++qs)
#pragma unroll
    for (int nt = 0; nt < 9; ++nt) acc[qs][nt] = (f32x4){0.f, 0.f, 0.f, 0.f};

#pragma unroll 1
  for (int kk = 0; kk < 6; ++kk) {
    bf16x8 af[2];
#pragma unroll
    for (int qs = 0; qs < 2; ++qs)
      af[qs] = *(const bf16x8*)(&As[(qs * 16 + l15) * 200 + kk * 32 + kq * 8]);
    const ushort_t* wp =
        Wsw + ((size_t)(kk * (N >> 4) + w * 9) << 9) + lane * 8;
#pragma unroll
    for (int nt = 0; nt < 9; ++nt) {
      U4BF8 wf;
      wf.u = *(const uint4*)(wp + (nt << 9));
#pragma unroll
      for (int qs = 0; qs < 2; ++qs)
        acc[qs][nt] = __builtin_amdgcn_mfma_f32_16x16x32_bf16(
            af[qs], wf.b, acc[qs][nt], 0, 0, 0);
    }
  }
  __syncthreads();  // As dead; smem reused for Q,K staging

  // --- phase 3: epilogue ---
  ushort_t* Cs = smem;
#pragma unroll
  for (int nt = 0; nt < 9; ++nt) {
    int t = w * 9 + nt;                  // 0..35 column tile
    int col = t * 16 + l15;
    float bb = bias[col];
    if (t < 24) {                        // Q,K -> LDS staging
#pragma unroll
      for (int qs = 0; qs < 2; ++qs)
#pragma unroll
        for (int r = 0; r < 4; ++r)
          Cs[(qs * 16 + kq * 4 + r) * CSB + col] = f2bf(acc[qs][nt][r] + bb);
    } else {                             // V -> Vt direct (bf16x4 packs)
      int vcol = col - 384;
      int h = vcol >> 5, d = vcol & 31;
      size_t vbase = ((size_t)((side * BB + batch) * HH + h) * 32 + d) * 512;
#pragma unroll
      for (int qs = 0; qs < 2; ++qs) {
        ushort_t pk[4];
#pragma unroll
        for (int r = 0; r < 4; ++r) pk[r] = f2bf(acc[qs][nt][r] + bb);
        *(uint2*)(Vt + vbase + k0 + qs * 16 + kq * 4) = *(const uint2*)(&pk[0]);
      }
    }
  }
  __syncthreads();
  // linear full-line store of Q,K rows (32 x 384 bf16)
  constexpr int UPR = 48;                // uint4 per row
#pragma unroll
  for (int i = 0; i < (32 * UPR) / 256; ++i) {
    int idx = tid + i * 256;
    int r = idx / UPR, u = idx - r * UPR;
    *(uint4*)(QK + (size_t)row0 * 384 + idx * 8) =
        *(const uint4*)(&Cs[r * CSB + u * 8]);
  }
}

// ---------------------------------------------------------------------------
// Fused O-projection + residual + LN-chain. Block = 32 rows x 192 cols.
// ---------------------------------------------------------------------------
__global__ __launch_bounds__(256) void oproj_ln_kernel(
    const ushort_t* __restrict__ A, const ushort_t* __restrict__ Wsw,
    const float* __restrict__ bias,
    const float* __restrict__ xa, const float* __restrict__ xb,
    const int* __restrict__ va, const int* __restrict__ vb,
    const float* __restrict__ g_oa, const float* __restrict__ b_oa,
    const float* __restrict__ g_ob, const float* __restrict__ b_ob,
    const float* __restrict__ g_f, const float* __restrict__ b_f,
    float* __restrict__ outf, ushort_t* __restrict__ outb) {
  __shared__ float smemf[32 * 196];      // 25 KB; As (12.8 KB) overlays
  ushort_t* As = (ushort_t*)smemf;

  int tid = threadIdx.x;
  int w = tid >> 6, lane = tid & 63, l15 = lane & 15, kq = lane >> 4;
  int row0 = blockIdx.x * 32;
  int side = row0 >= ROWS;
  int rb = row0 - side * ROWS;

  // stage A (attO) 32x192 bf16
  {
    const ushort_t* ap = A + (size_t)row0 * DD;
#pragma unroll
    for (int i = 0; i < 3; ++i) {
      int idx = tid + i * 256;
      int r = idx / 24, c = (idx - r * 24) * 8;
      *(uint4*)(&As[r * 200 + c]) = *(const uint4*)(ap + idx * 8);
    }
  }
  __syncthreads();

  f32x4 acc[2][3];
#pragma unroll
  for (int qs = 0; qs < 2; ++qs)
#pragma unroll
    for (int nt = 0; nt < 3; ++nt) acc[qs][nt] = (f32x4){0.f, 0.f, 0.f, 0.f};

#pragma unroll 1
  for (int kk = 0; kk < 6; ++kk) {
    bf16x8 af[2];
#pragma unroll
    for (int qs = 0; qs < 2; ++qs)
      af[qs] = *(const bf16x8*)(&As[(qs * 16 + l15) * 200 + kk * 32 + kq * 8]);
    const ushort_t* wp =
        Wsw + ((size_t)(kk * (192 >> 4) + w * 3) << 9) + lane * 8;
#pragma unroll
    for (int nt = 0; nt < 3; ++nt) {
      U4BF8 wf;
      wf.u = *(const uint4*)(wp + (nt << 9));
#pragma unroll
      for (int qs = 0; qs < 2; ++qs)
        acc[qs][nt] = __builtin_amdgcn_mfma_f32_16x16x32_bf16(
            af[qs], wf.b, acc[qs][nt], 0, 0, 0);
    }
  }
  __syncthreads();  // As dead

  // stage C + bias -> Cs fp32
  float* Cs = smemf;
#pragma unroll
  for (int nt = 0; nt < 3; ++nt) {
    int col = (w * 3 + nt) * 16 + l15;
    float bb = bias[col];
#pragma unroll
    for (int qs = 0; qs < 2; ++qs)
#pragma unroll
      for (int r = 0; r < 4; ++r)
        Cs[(qs * 16 + kq * 4 + r) * 196 + col] = acc[qs][nt][r] + bb;
  }
  __syncthreads();

  // row phase: 8 threads/row, interleaved cols (col = j*32 + l8*4)
  int row = tid >> 3, l8 = tid & 7;
  int grow = row0 + row;
  const float* xrow = (side ? xb : xa) + (size_t)(rb + row) * DD;
  const float* crow = &Cs[row * 196];
  float v[24];
  float s = 0.f;
#pragma unroll
  for (int j = 0; j < 6; ++j) {
    int col = j * 32 + l8 * 4;
    float4 q = *(const float4*)(xrow + col);
    v[j*4+0] = crow[col+0] + q.x; v[j*4+1] = crow[col+1] + q.y;
    v[j*4+2] = crow[col+2] + q.z; v[j*4+3] = crow[col+3] + q.w;
    s += v[j*4+0] + v[j*4+1] + v[j*4+2] + v[j*4+3];
  }
  s += __shfl_xor(s, 1); s += __shfl_xor(s, 2); s += __shfl_xor(s, 4);
  float mu = s * (1.0f / 192.0f);
  float ss = 0.f;
#pragma unroll
  for (int j = 0; j < 24; ++j) { float d = v[j] - mu; ss += d * d; }
  ss += __shfl_xor(ss, 1); ss += __shfl_xor(ss, 2); ss += __shfl_xor(ss, 4);
  float inv = rsqrtf(ss * (1.0f / 192.0f) + 1e-5f);
  int vld = (side ? vb : va)[rb + row];
  const float* g1 = side ? g_ob : g_oa;
  const float* b1 = side ? b_ob : b_oa;
  float y[24];
#pragma unroll
  for (int j = 0; j < 6; ++j) {
#pragma unroll
    for (int e = 0; e < 4; ++e) {
      int col = j * 32 + l8 * 4 + e;
      float vv = v[j * 4 + e];
      y[j * 4 + e] = vld ? (vv - mu) * inv * g1[col] + b1[col] : vv;
    }
  }
  float* orow = outf + (size_t)grow * DD;
#pragma unroll
  for (int j = 0; j < 6; ++j) {
    float4 q = {y[j*4+0], y[j*4+1], y[j*4+2], y[j*4+3]};
    *(float4*)(orow + j * 32 + l8 * 4) = q;
  }
  // LN2 -> bf16
  float s2 = 0.f;
#pragma unroll
  for (int j = 0; j < 24; ++j) s2 += y[j];
  s2 += __shfl_xor(s2, 1); s2 += __shfl_xor(s2, 2); s2 += __shfl_xor(s2, 4);
  float mu2 = s2 * (1.0f / 192.0f);
  float ss2 = 0.f;
#pragma unroll
  for (int j = 0; j < 24; ++j) { float e = y[j] - mu2; ss2 += e * e; }
  ss2 += __shfl_xor(ss2, 1); ss2 += __shfl_xor(ss2, 2); ss2 += __shfl_xor(ss2, 4);
  float inv2 = rsqrtf(ss2 * (1.0f / 192.0f) + 1e-5f);
  ushort_t* obrow = outb + (size_t)grow * DD;
#pragma unroll
  for (int j = 0; j < 6; ++j) {
    ushort_t zb[4];
#pragma unroll
    for (int e = 0; e < 4; ++e) {
      int col = j * 32 + l8 * 4 + e;
      float z = vld ? (y[j*4+e] - mu2) * inv2 * g_f[col] + b_f[col] : y[j*4+e];
      zb[e] = f2bf(z);
    }
    *(uint2*)(obrow + j * 32 + l8 * 4) = *(const uint2*)(&zb[0]);
  }
}

// ---------------------------------------------------------------------------
// Fused FFN + final residual + LN. 256 threads (4 waves), 64 rows/block.
// ---------------------------------------------------------------------------
__global__ __launch_bounds__(256, 3) void ffn_fused_kernel(
    const ushort_t* __restrict__ A, const ushort_t* __restrict__ W1t,
    const float* __restrict__ bias1, const ushort_t* __restrict__ W2t,
    const float* __restrict__ bias2,
    const int* __restrict__ va, const int* __restrict__ vb,
    const float* __restrict__ g_f, const float* __restrict__ b_f,
    float* __restrict__ outf) {
  __shared__ float smemf[64 * 196];      // 50.2 KB epilogue Cs; overlays:
  ushort_t* As = (ushort_t*)smemf;       //   As 64*200 us (25.6 KB)
  ushort_t* Hs = As + 64 * 200;          //   Hs 2*64*72 us (18.4 KB)

  int tid = threadIdx.x;
  int w = tid >> 6;
  int lane = tid & 63;
  int l15 = lane & 15;
  int kq = lane >> 4;
  int row0 = blockIdx.x * 64;
  int side = row0 >= ROWS;
  int rb0 = row0 - side * ROWS;

  // stage A: 64 rows x 24 uint4 = 1536 / 256 threads = 6 each
#pragma unroll
  for (int i = 0; i < 6; ++i) {
    int idx = tid + i * 256;
    int r = idx / 24, c = (idx % 24) * 8;
    *(uint4*)(&As[r * 200 + c]) = *(const uint4*)(A + (size_t)(row0 + r) * DD + c);
  }

  const ushort_t* w1p = W1t + (size_t)(w * 16 + l15) * DD + kq * 8;
  const ushort_t* w2p = W2t + (size_t)(w * 48 + l15) * HID + kq * 8;

  U4BF8 w1f[6], w1n[6], w2f[6];
#pragma unroll
  for (int kk = 0; kk < 6; ++kk)
    w1f[kk].u = *(const uint4*)(w1p + kk * 32);  // hc = 0

  f32x4 Cacc[4][3];
#pragma unroll
  for (int qs = 0; qs < 4; ++qs)
#pragma unroll
    for (int nt = 0; nt < 3; ++nt) Cacc[qs][nt] = (f32x4){0.f, 0.f, 0.f, 0.f};

  __syncthreads();   // As ready

  for (int hc = 0; hc < 12; ++hc) {
#pragma unroll
    for (int kk2 = 0; kk2 < 2; ++kk2)
#pragma unroll
      for (int nt = 0; nt < 3; ++nt)
        w2f[kk2 * 3 + nt].u =
            *(const uint4*)(w2p + (size_t)(nt * 16) * HID + hc * 64 + kk2 * 32);

    f32x4 Hacc[4];
#pragma unroll
    for (int qs = 0; qs < 4; ++qs) Hacc[qs] = (f32x4){0.f, 0.f, 0.f, 0.f};
#pragma unroll
    for (int kk = 0; kk < 6; ++kk) {
#pragma unroll
      for (int qs = 0; qs < 4; ++qs) {
        bf16x8 af = *(const bf16x8*)(&As[(qs * 16 + l15) * 200 + kk * 32 + kq * 8]);
        Hacc[qs] = __builtin_amdgcn_mfma_f32_16x16x32_bf16(
            af, w1f[kk].b, Hacc[qs], 0, 0, 0);
      }
    }

    if (hc < 11) {
#pragma unroll
      for (int kk = 0; kk < 6; ++kk)
        w1n[kk].u = *(const uint4*)(w1p + (size_t)(hc + 1) * 64 * DD + kk * 32);
    }

    {
      float bb = bias1[hc * 64 + w * 16 + l15];
      ushort_t* hb = &Hs[(hc & 1) * 4608];
#pragma unroll
      for (int qs = 0; qs < 4; ++qs)
#pragma unroll
        for (int r = 0; r < 4; ++r) {
          float x = Hacc[qs][r] + bb;
          x = 0.5f * x * (1.0f + erff(x * 0.70710678118654752f));
          hb[(qs * 16 + kq * 4 + r) * 72 + w * 16 + l15] = f2bf(x);
        }
    }
    __syncthreads();

#pragma unroll
    for (int kk2 = 0; kk2 < 2; ++kk2) {
      bf16x8 hf[4];
#pragma unroll
      for (int qs = 0; qs < 4; ++qs)
        hf[qs] = *(const bf16x8*)(&Hs[(hc & 1) * 4608 +
                                      (qs * 16 + l15) * 72 + kk2 * 32 + kq * 8]);
#pragma unroll
      for (int nt = 0; nt < 3; ++nt)
#pragma unroll
        for (int qs = 0; qs < 4; ++qs)
          Cacc[qs][nt] = __builtin_amdgcn_mfma_f32_16x16x32_bf16(
              hf[qs], w2f[kk2 * 3 + nt].b, Cacc[qs][nt], 0, 0, 0);
    }

#pragma unroll
    for (int kk = 0; kk < 6; ++kk) w1f[kk] = w1n[kk];
  }
  __syncthreads();   // As/Hs dead; smemf becomes epilogue Cs

  // epilogue: stage C + bias2, then per-row residual + masked LN
  float* Cs = smemf;
#pragma unroll
  for (int qs = 0; qs < 4; ++qs)
#pragma unroll
    for (int nt = 0; nt < 3; ++nt) {
      int col = w * 48 + nt * 16 + l15;
      float bb = bias2[col];
#pragma unroll
      for (int r = 0; r < 4; ++r)
        Cs[(qs * 16 + kq * 4 + r) * 196 + col] = Cacc[qs][nt][r] + bb;
    }
  __syncthreads();

  // 4 threads/row, interleaved cols (col = j*16 + l4*4)
  int row = tid >> 2, l4 = tid & 3;
  int grow = row0 + row;
  float* orow = outf + (size_t)grow * DD;
  const float* crow = &Cs[row * 196];
  float v[48];
  float s = 0.f;
#pragma unroll
  for (int j = 0; j < 12; ++j) {
    int col = j * 16 + l4 * 4;
    float4 q = *(const float4*)(orow + col);   // residual (in-place read)
    v[j*4+0] = crow[col+0] + q.x; v[j*4+1] = crow[col+1] + q.y;
    v[j*4+2] = crow[col+2] + q.z; v[j*4+3] = crow[col+3] + q.w;
    s += v[j*4+0] + v[j*4+1] + v[j*4+2] + v[j*4+3];
  }
  s += __shfl_xor(s, 1); s += __shfl_xor(s, 2);
  float mu = s * (1.0f / 192.0f);
  float ss = 0.f;
#pragma unroll
  for (int j = 0; j < 48; ++j) { float d = v[j] - mu; ss += d * d; }
  ss += __shfl_xor(ss, 1); ss += __shfl_xor(ss, 2);
  float inv = rsqrtf(ss * (1.0f / 192.0f) + 1e-5f);
  int vld = (side ? vb : va)[rb0 + row];
#pragma unroll
  for (int j = 0; j < 12; ++j) {
    int col = j * 16 + l4 * 4;
    float4 q;
#pragma unroll
    for (int e = 0; e < 4; ++e) {
      float vv = v[j * 4 + e];
      ((float*)&q)[e] = vld ? (vv - mu) * inv * g_f[col + e] + b_f[col + e] : vv;
    }
    *(float4*)(orow + col) = q;
  }
}

// ---------------------------------------------------------------------------
// MFMA flash attention v6: SWAPPED QK^T (S^T = mfma(K,Q)) -> lane-local
// softmax row (q = lane&15), P packed via v_cvt_pk_bf16_f32 and
// redistributed into PV A-fragments with shuffles. ZERO LDS, zero barriers.
// ---------------------------------------------------------------------------
__global__ __launch_bounds__(256) void attn_mfma_kernel(
    const ushort_t* __restrict__ QK, const ushort_t* __restrict__ Vt,
    const int* __restrict__ valid_a, const int* __restrict__ valid_b,
    ushort_t* __restrict__ out) {
  int i = blockIdx.x;
  int gid = ((i >> 5) << 3) | (i & 7);
  int qt = (i >> 3) & 3;
  int side = gid >= BB * HH;
  int grem = side ? gid - BB * HH : gid;
  int h = grem % HH;
  int batch = grem / HH;
  int tid = threadIdx.x;
  int w = tid >> 6;
  int lane = tid & 63;
  int l15 = lane & 15;
  int kq = lane >> 4;

  const int* validq = side ? valid_b : valid_a;
  const int* validk = side ? valid_a : valid_b;
  size_t qrow0  = (size_t)side * ROWS + (size_t)batch * LL;
  size_t kvrow0 = (size_t)(1 - side) * ROWS + (size_t)batch * LL;
  const ushort_t* vtp =
      Vt + ((size_t)(((1 - side) * BB + batch) * HH + h) * 32) * 512;

  int qbase = qt * 128 + w * 32;

  // Q fragments (B-operand): Q[q = g*16+l15][d = kq*8..+8]
  U4BF8 qfrag[2];
#pragma unroll
  for (int g = 0; g < 2; ++g)
    qfrag[g].u = *(const uint4*)(QK + (qrow0 + qbase + g * 16 + l15) * 384 +
                                 h * DKK + kq * 8);

  // per-group scalar q-mask coefficients (lane's q = g*16 + l15)
  float sqf[2], mq[2];
#pragma unroll
  for (int g = 0; g < 2; ++g) {
    int vq = validq[batch * LL + qbase + g * 16 + l15];
    sqf[g] = vq ? SB2 : 0.0f;
    mq[g]  = vq ? 0.0f : MASKED_X;
  }

  float lsum[2] = {0.f, 0.f};
  f32x4 Oacc[2][2];
#pragma unroll
  for (int g = 0; g < 2; ++g)
#pragma unroll
    for (int ds = 0; ds < 2; ++ds) Oacc[g][ds] = (f32x4){0.f, 0.f, 0.f, 0.f};

  // shuffle source lanes for P redistribution
  int slA = l15 + ((kq & 1) << 5);     // l15 + 16*(2*(kq&1))
  int slB = slA + 16;
  int hi = kq >> 1;

  for (int c = 0; c < LL; c += 64) {
    // packed P: pk[g][t][jj] = bf16x2 {p[t][2jj], p[t][2jj+1]},
    // lane holds P[q=g*16+l15][k = c + 16t + 4*kq + r]
    uint_t pk[2][4][2];
#pragma unroll
    for (int t = 0; t < 4; ++t) {
      U4BF8 kf;
      kf.u = *(const uint4*)(QK + (kvrow0 + c + t * 16 + l15) * 384 +
                             192 + h * DKK + kq * 8);
      int4 vk = *(const int4*)(validk + batch * LL + c + t * 16 + kq * 4);
      f32x4 z = (f32x4){0.f, 0.f, 0.f, 0.f};
      f32x4 S0 = __builtin_amdgcn_mfma_f32_16x16x32_bf16(kf.b, qfrag[0].b, z, 0, 0, 0);
      f32x4 S1 = __builtin_amdgcn_mfma_f32_16x16x32_bf16(kf.b, qfrag[1].b, z, 0, 0, 0);
      float mkb[4];
      mkb[0] = vk.x ? 0.0f : MASKED_X;
      mkb[1] = vk.y ? 0.0f : MASKED_X;
      mkb[2] = vk.z ? 0.0f : MASKED_X;
      mkb[3] = vk.w ? 0.0f : MASKED_X;
      float p0[4], p1[4];
#pragma unroll
      for (int r = 0; r < 4; ++r) {
        p0[r] = __builtin_amdgcn_exp2f(fmaf(S0[r], sqf[0], fminf(mq[0], mkb[r])));
        p1[r] = __builtin_amdgcn_exp2f(fmaf(S1[r], sqf[1], fminf(mq[1], mkb[r])));
        lsum[0] += p0[r];
        lsum[1] += p1[r];
      }
      pk[0][t][0] = cvtpk(p0[0], p0[1]); pk[0][t][1] = cvtpk(p0[2], p0[3]);
      pk[1][t][0] = cvtpk(p1[0], p1[1]); pk[1][t][1] = cvtpk(p1[2], p1[3]);
    }

    // redistribute to PV A-fragments + PV, per 32-k chunk
#pragma unroll
    for (int cc = 0; cc < 2; ++cc) {
      U4BF8 pa[2];
#pragma unroll
      for (int g = 0; g < 2; ++g) {
        uint_t d[4];
#pragma unroll
        for (int j = 0; j < 4; ++j) {
          int sl = (j < 2) ? slA : slB;
          uint_t v0 = (uint_t)__shfl((int)pk[g][2 * cc][j & 1], sl, 64);
          uint_t v1 = (uint_t)__shfl((int)pk[g][2 * cc + 1][j & 1], sl, 64);
          d[j] = hi ? v1 : v0;
        }
        pa[g].u = make_uint4(d[0], d[1], d[2], d[3]);
      }
      bf16x8 vf[2];
#pragma unroll
      for (int ds = 0; ds < 2; ++ds)
        vf[ds] = *(const bf16x8*)(vtp + (size_t)(ds * 16 + l15) * 512 +
                                  c + cc * 32 + kq * 8);
#pragma unroll
      for (int g = 0; g < 2; ++g)
#pragma unroll
        for (int ds = 0; ds < 2; ++ds)
          Oacc[g][ds] = __builtin_amdgcn_mfma_f32_16x16x32_bf16(
              pa[g].b, vf[ds], Oacc[g][ds], 0, 0, 0);
    }
  }

  // lsum: sum across kq groups (lane bits 4,5) -> every lane has sum for q=l15
#pragma unroll
  for (int g = 0; g < 2; ++g) {
    lsum[g] += __shfl_xor(lsum[g], 16);
    lsum[g] += __shfl_xor(lsum[g], 32);
  }

  // output lane (kq,r) needs lsum of q = kq*4+r
#pragma unroll
  for (int g = 0; g < 2; ++g)
#pragma unroll
    for (int ds = 0; ds < 2; ++ds)
#pragma unroll
      for (int r = 0; r < 4; ++r) {
        float ls = __shfl(lsum[g], kq * 4 + r, 64);
        int q = qbase + g * 16 + kq * 4 + r;
        out[(qrow0 + q) * DD + h * DKK + ds * 16 + l15] =
            f2bf(Oacc[g][ds][r] / ls);
      }
}

// ---------------------------------------------------------------------------
extern "C" void kernel_launch(void* const* d_in, const int* in_sizes, int n_in,
                              void* d_out, int out_size, void* d_ws, size_t ws_size,
                              hipStream_t stream) {
  const float* x_a = (const float*)d_in[0];
  const float* x_b = (const float*)d_in[1];
  const int* valid_a = (const int*)d_in[2];
  const int* valid_b = (const int*)d_in[3];
  const float* ln_a_g = (const float*)d_in[4];
  const float* ln_a_b = (const float*)d_in[5];
  const float* ln_b_g = (const float*)d_in[6];
  const float* ln_b_b = (const float*)d_in[7];
  const float* ln_oa_g = (const float*)d_in[8];
  const float* ln_oa_b = (const float*)d_in[9];
  const float* ln_ob_g = (const float*)d_in[10];
  const float* ln_ob_b = (const float*)d_in[11];
  const float* wq = (const float*)d_in[12];
  const float* bq = (const float*)d_in[13];
  const float* wk = (const float*)d_in[14];
  const float* bk = (const float*)d_in[15];
  const float* wv = (const float*)d_in[16];
  const float* bv = (const float*)d_in[17];
  const float* wo = (const float*)d_in[18];
  const float* bo = (const float*)d_in[19];
  const float* fln_g = (const float*)d_in[20];
  const float* fln_b = (const float*)d_in[21];
  const float* flno_g = (const float*)d_in[22];
  const float* flno_b = (const float*)d_in[23];
  const float* w1 = (const float*)d_in[24];
  const float* b1 = (const float*)d_in[25];
  const float* w2 = (const float*)d_in[26];
  const float* b2 = (const float*)d_in[27];

  // Workspace: weights [0, 887040); lnFull/attO bf16 [2R,192] at 887040;
  // QK bf16 [2R,384] at 19761408 (ends 57510144);
  // Vt bf16 [2*BB*HH*32][512] at 57510144 (ends 76384512).
  char* wsb = (char*)d_ws;
  ushort_t* Wqkv = (ushort_t*)wsb;
  ushort_t* Wo_t = Wqkv + 110592;
  ushort_t* W1_t = Wo_t + 36864;
  ushort_t* W2_t = W1_t + 147456;
  float*    bqkv = (float*)(W2_t + 147456);
  ushort_t* lnFull = (ushort_t*)(wsb + 887040);
  ushort_t* attO   = lnFull;
  ushort_t* QK = (ushort_t*)(wsb + 19761408);
  ushort_t* Vt = (ushort_t*)(wsb + 57510144);

  float* out_a = (float*)d_out;   // [2R,192] fp32 contiguous

  dim3 b256(256);
  dim3 gGemm(2 * ROWS / 32);                    // 1536 row-blocks
  dim3 gAttn(BB * HH * 4 * 2);                  // 2304
  dim3 gFFN(2 * ROWS / 64);                     // 768

  hipLaunchKernelGGL(pack_kernel, dim3(1731), b256, 0, stream,
                     wq, wk, wv, wo, w1, w2, bq, bk, bv,
                     Wqkv, Wo_t, W1_t, W2_t, bqkv);

  // 1+2. fused pre-LN + QKV projection; V written pre-transposed
  hipLaunchKernelGGL(qkv_ln_kernel, gGemm, b256, 0, stream,
                     x_a, x_b, valid_a, valid_b,
                     ln_a_g, ln_a_b, ln_b_g, ln_b_b,
                     Wqkv, bqkv, QK, Vt);

  // 3. attention (swapped QK^T, in-register softmax, zero LDS)
  hipLaunchKernelGGL(attn_mfma_kernel, gAttn, b256, 0, stream,
                     QK, Vt, valid_a, valid_b, attO);

  // 4+5+6. fused O-proj + residual-LN -> d_out, FFN pre-LN -> lnFull bf16
  hipLaunchKernelGGL(oproj_ln_kernel, gGemm, b256, 0, stream,
                     attO, Wo_t, bo, x_a, x_b, valid_a, valid_b,
                     ln_oa_g, ln_oa_b, ln_ob_g, ln_ob_b, fln_g, fln_b,
                     out_a, lnFull);

  // 7+8. fused FFN + final residual + LN -> d_out (in place)
  hipLaunchKernelGGL(ffn_fused_kernel, gFFN, b256, 0, stream,
                     lnFull, W1_t, b1, W2_t, b2, valid_a, valid_b,
                     flno_g, flno_b, out_a);
}

// Round 9
// 356.305 us; speedup vs baseline: 1.0976x; 1.0962x over previous
//
#include <hip/hip_runtime.h>
#include <math.h>

#define BB 48
#define LL 512
#define DD 192
#define HH 6
#define DKK 32
#define HID 768
#define ROWS (BB * LL)
#define BLD ((size_t)ROWS * DD)
#define SB2 0.25503531f                 // (1/sqrt(32)) * log2(e)
#define MASKED_X (-36.0f)               // exp2(-36) ~= 1.5e-11 (uniform floor)

typedef unsigned short ushort_t;
typedef unsigned int uint_t;
typedef __bf16 bf16x8 __attribute__((ext_vector_type(8)));
typedef float f32x4 __attribute__((ext_vector_type(4)));

union U4BF8 { uint4 u; bf16x8 b; };
union BFU { __bf16 h; ushort_t u; };

__device__ __forceinline__ ushort_t f2bf(float f) {
  union { float f; uint_t u; } v; v.f = f;
  uint_t r = v.u + 0x7fffu + ((v.u >> 16) & 1u);
  return (ushort_t)(r >> 16);
}
__device__ __forceinline__ ushort_t cvt_bf(float f) {
  BFU c; c.h = (__bf16)f; return c.u;
}

// Swizzled weight offset: fragment-major so a wave's dwordx4 load of one
// 16x32 (n x k) MFMA B-tile is lane-linear (fully coalesced 1KB/wave).
__device__ __forceinline__ int swz_w(int n, int k, int N) {
  return ((k >> 5) * (N >> 4) + (n >> 4)) * 512 +
         ((((k & 31) >> 3) << 4) + (n & 15)) * 8 + (k & 7);
}

// ---------------------------------------------------------------------------
__global__ __launch_bounds__(256) void pack_kernel(
    const float* __restrict__ wq, const float* __restrict__ wk,
    const float* __restrict__ wv, const float* __restrict__ wo,
    const float* __restrict__ w1, const float* __restrict__ w2,
    const float* __restrict__ bq, const float* __restrict__ bk,
    const float* __restrict__ bv,
    ushort_t* __restrict__ Wqkv, ushort_t* __restrict__ Wo,
    ushort_t* __restrict__ W1, ushort_t* __restrict__ W2,
    float* __restrict__ bqkv) {
  int i = blockIdx.x * 256 + threadIdx.x;
  if (i < 110592) {                       // Wqkv swizzled, N=576
    int n2 = i / 192, k = i - n2 * 192;
    int part = n2 / 192, n = n2 - part * 192;
    const float* src = part == 0 ? wq : (part == 1 ? wk : wv);
    Wqkv[swz_w(n2, k, 576)] = f2bf(src[k * 192 + n]);
  } else if (i < 147456) {                // Wo swizzled, N=192
    int j = i - 110592;
    int n = j / 192, k = j - n * 192;
    Wo[swz_w(n, k, 192)] = f2bf(wo[k * 192 + n]);
  } else if (i < 294912) {                // W1_t [768][192]
    int j = i - 147456;
    int n = j / 192, k = j - n * 192;
    W1[j] = f2bf(w1[k * 768 + n]);
  } else if (i < 442368) {                // W2_t [192][768]
    int j = i - 294912;
    int n = j / 768, k = j - n * 768;
    W2[j] = f2bf(w2[k * 192 + n]);
  } else if (i < 442944) {                // bqkv [576]
    int j = i - 442368;
    bqkv[j] = j < 192 ? bq[j] : (j < 384 ? bk[j - 192] : bv[j - 384]);
  }
}

// ---------------------------------------------------------------------------
// Fused pre-LN + QKV projection. Block = 32 rows x 576 cols, 256 threads.
// ---------------------------------------------------------------------------
__global__ __launch_bounds__(256) void qkv_ln_kernel(
    const float* __restrict__ xa, const float* __restrict__ xb,
    const int* __restrict__ va, const int* __restrict__ vb,
    const float* __restrict__ g_a, const float* __restrict__ b_a,
    const float* __restrict__ g_b, const float* __restrict__ b_b,
    const ushort_t* __restrict__ Wsw, const float* __restrict__ bias,
    ushort_t* __restrict__ Cb) {
  constexpr int N = 576;
  constexpr int CSB = N + 8;
  __shared__ ushort_t smem[32 * CSB];    // 37.4 KB; As (12.8 KB) overlays
  ushort_t* As = smem;

  int tid = threadIdx.x;
  int w = tid >> 6, lane = tid & 63, l15 = lane & 15, kq = lane >> 4;
  int row0 = blockIdx.x * 32;
  int side = row0 >= ROWS;
  int rb = row0 - side * ROWS;

  // --- phase 1: masked LN, x fp32 -> As bf16 ---
  {
    int row = tid >> 3, l8 = tid & 7;
    const float* xr = (side ? xb : xa) + (size_t)(rb + row) * DD + l8 * 24;
    float v[24];
    float s = 0.f;
#pragma unroll
    for (int j = 0; j < 6; ++j) {
      float4 q = *(const float4*)(xr + j * 4);
      v[j*4+0] = q.x; v[j*4+1] = q.y; v[j*4+2] = q.z; v[j*4+3] = q.w;
      s += q.x + q.y + q.z + q.w;
    }
    s += __shfl_xor(s, 1); s += __shfl_xor(s, 2); s += __shfl_xor(s, 4);
    float mu = s * (1.0f / 192.0f);
    float ss = 0.f;
#pragma unroll
    for (int j = 0; j < 24; ++j) { float d = v[j] - mu; ss += d * d; }
    ss += __shfl_xor(ss, 1); ss += __shfl_xor(ss, 2); ss += __shfl_xor(ss, 4);
    float inv = rsqrtf(ss * (1.0f / 192.0f) + 1e-5f);
    int vld = (side ? vb : va)[rb + row];
    const float* g = side ? g_b : g_a;
    const float* be = side ? b_b : b_a;
    ushort_t ob[24];
#pragma unroll
    for (int j = 0; j < 24; ++j) {
      int col = l8 * 24 + j;
      float r = vld ? (v[j] - mu) * inv * g[col] + be[col] : v[j];
      ob[j] = f2bf(r);
    }
#pragma unroll
    for (int j = 0; j < 3; ++j)
      *(uint4*)(&As[row * 200 + l8 * 24 + j * 8]) = *(const uint4*)(&ob[j * 8]);
  }
  __syncthreads();

  // --- phase 2: GEMM ---
  f32x4 acc[2][9];
#pragma unroll
  for (int qs = 0; qs < 2; ++qs)
#pragma unroll
    for (int nt = 0; nt < 9; ++nt) acc[qs][nt] = (f32x4){0.f, 0.f, 0.f, 0.f};

#pragma unroll 1
  for (int kk = 0; kk < 6; ++kk) {
    bf16x8 af[2];
#pragma unroll
    for (int qs = 0; qs < 2; ++qs)
      af[qs] = *(const bf16x8*)(&As[(qs * 16 + l15) * 200 + kk * 32 + kq * 8]);
    const ushort_t* wp =
        Wsw + ((size_t)(kk * (N >> 4) + w * 9) << 9) + lane * 8;
#pragma unroll
    for (int nt = 0; nt < 9; ++nt) {
      U4BF8 wf;
      wf.u = *(const uint4*)(wp + (nt << 9));
#pragma unroll
      for (int qs = 0; qs < 2; ++qs)
        acc[qs][nt] = __builtin_amdgcn_mfma_f32_16x16x32_bf16(
            af[qs], wf.b, acc[qs][nt], 0, 0, 0);
    }
  }
  __syncthreads();  // As dead; smem reused for C staging

  // --- phase 3: bias -> LDS -> linear full-line bf16 stores ---
  ushort_t* Cs = smem;
#pragma unroll
  for (int nt = 0; nt < 9; ++nt) {
    int col = (w * 9 + nt) * 16 + l15;
    float bb = bias[col];
#pragma unroll
    for (int qs = 0; qs < 2; ++qs)
#pragma unroll
      for (int r = 0; r < 4; ++r)
        Cs[(qs * 16 + kq * 4 + r) * CSB + col] = f2bf(acc[qs][nt][r] + bb);
  }
  __syncthreads();
  constexpr int UPR = (N * 2) / 16;
#pragma unroll
  for (int i = 0; i < (32 * UPR) / 256; ++i) {
    int idx = tid + i * 256;
    int r = idx / UPR, u = idx - r * UPR;
    *(uint4*)(Cb + (size_t)row0 * N + idx * 8) =
        *(const uint4*)(&Cs[r * CSB + u * 8]);
  }
}

// ---------------------------------------------------------------------------
// Fused O-projection + residual + LN-chain. Block = 32 rows x 192 cols.
// Row phase uses INTERLEAVED col ownership (col = j*32 + l8*4) so wave
// stores are full 64B-line contiguous (no write-allocate RMW).
// ---------------------------------------------------------------------------
__global__ __launch_bounds__(256) void oproj_ln_kernel(
    const ushort_t* __restrict__ A, const ushort_t* __restrict__ Wsw,
    const float* __restrict__ bias,
    const float* __restrict__ xa, const float* __restrict__ xb,
    const int* __restrict__ va, const int* __restrict__ vb,
    const float* __restrict__ g_oa, const float* __restrict__ b_oa,
    const float* __restrict__ g_ob, const float* __restrict__ b_ob,
    const float* __restrict__ g_f, const float* __restrict__ b_f,
    float* __restrict__ outf, ushort_t* __restrict__ outb) {
  __shared__ float smemf[32 * 196];      // 25 KB; As (12.8 KB) overlays
  ushort_t* As = (ushort_t*)smemf;

  int tid = threadIdx.x;
  int w = tid >> 6, lane = tid & 63, l15 = lane & 15, kq = lane >> 4;
  int row0 = blockIdx.x * 32;
  int side = row0 >= ROWS;
  int rb = row0 - side * ROWS;

  // stage A (attO) 32x192 bf16
  {
    const ushort_t* ap = A + (size_t)row0 * DD;
#pragma unroll
    for (int i = 0; i < 3; ++i) {
      int idx = tid + i * 256;
      int r = idx / 24, c = (idx - r * 24) * 8;
      *(uint4*)(&As[r * 200 + c]) = *(const uint4*)(ap + idx * 8);
    }
  }
  __syncthreads();

  f32x4 acc[2][3];
#pragma unroll
  for (int qs = 0; qs < 2; ++qs)
#pragma unroll
    for (int nt = 0; nt < 3; ++nt) acc[qs][nt] = (f32x4){0.f, 0.f, 0.f, 0.f};

#pragma unroll 1
  for (int kk = 0; kk < 6; ++kk) {
    bf16x8 af[2];
#pragma unroll
    for (int qs = 0; qs < 2; ++qs)
      af[qs] = *(const bf16x8*)(&As[(qs * 16 + l15) * 200 + kk * 32 + kq * 8]);
    const ushort_t* wp =
        Wsw + ((size_t)(kk * (192 >> 4) + w * 3) << 9) + lane * 8;
#pragma unroll
    for (int nt = 0; nt < 3; ++nt) {
      U4BF8 wf;
      wf.u = *(const uint4*)(wp + (nt << 9));
#pragma unroll
      for (int qs = 0; qs < 2; ++qs)
        acc[qs][nt] = __builtin_amdgcn_mfma_f32_16x16x32_bf16(
            af[qs], wf.b, acc[qs][nt], 0, 0, 0);
    }
  }
  __syncthreads();  // As dead

  // stage C + bias -> Cs fp32
  float* Cs = smemf;
#pragma unroll
  for (int nt = 0; nt < 3; ++nt) {
    int col = (w * 3 + nt) * 16 + l15;
    float bb = bias[col];
#pragma unroll
    for (int qs = 0; qs < 2; ++qs)
#pragma unroll
      for (int r = 0; r < 4; ++r)
        Cs[(qs * 16 + kq * 4 + r) * 196 + col] = acc[qs][nt][r] + bb;
  }
  __syncthreads();

  // row phase: 8 threads/row, interleaved cols (col = j*32 + l8*4)
  int row = tid >> 3, l8 = tid & 7;
  int grow = row0 + row;
  const float* xrow = (side ? xb : xa) + (size_t)(rb + row) * DD;
  const float* crow = &Cs[row * 196];
  float v[24];
  float s = 0.f;
#pragma unroll
  for (int j = 0; j < 6; ++j) {
    int col = j * 32 + l8 * 4;
    float4 q = *(const float4*)(xrow + col);
    v[j*4+0] = crow[col+0] + q.x; v[j*4+1] = crow[col+1] + q.y;
    v[j*4+2] = crow[col+2] + q.z; v[j*4+3] = crow[col+3] + q.w;
    s += v[j*4+0] + v[j*4+1] + v[j*4+2] + v[j*4+3];
  }
  s += __shfl_xor(s, 1); s += __shfl_xor(s, 2); s += __shfl_xor(s, 4);
  float mu = s * (1.0f / 192.0f);
  float ss = 0.f;
#pragma unroll
  for (int j = 0; j < 24; ++j) { float d = v[j] - mu; ss += d * d; }
  ss += __shfl_xor(ss, 1); ss += __shfl_xor(ss, 2); ss += __shfl_xor(ss, 4);
  float inv = rsqrtf(ss * (1.0f / 192.0f) + 1e-5f);
  int vld = (side ? vb : va)[rb + row];
  const float* g1 = side ? g_ob : g_oa;
  const float* b1 = side ? b_ob : b_oa;
  float y[24];
#pragma unroll
  for (int j = 0; j < 6; ++j) {
#pragma unroll
    for (int e = 0; e < 4; ++e) {
      int col = j * 32 + l8 * 4 + e;
      float vv = v[j * 4 + e];
      y[j * 4 + e] = vld ? (vv - mu) * inv * g1[col] + b1[col] : vv;
    }
  }
  float* orow = outf + (size_t)grow * DD;
#pragma unroll
  for (int j = 0; j < 6; ++j) {
    float4 q = {y[j*4+0], y[j*4+1], y[j*4+2], y[j*4+3]};
    *(float4*)(orow + j * 32 + l8 * 4) = q;
  }
  // LN2 -> bf16
  float s2 = 0.f;
#pragma unroll
  for (int j = 0; j < 24; ++j) s2 += y[j];
  s2 += __shfl_xor(s2, 1); s2 += __shfl_xor(s2, 2); s2 += __shfl_xor(s2, 4);
  float mu2 = s2 * (1.0f / 192.0f);
  float ss2 = 0.f;
#pragma unroll
  for (int j = 0; j < 24; ++j) { float e = y[j] - mu2; ss2 += e * e; }
  ss2 += __shfl_xor(ss2, 1); ss2 += __shfl_xor(ss2, 2); ss2 += __shfl_xor(ss2, 4);
  float inv2 = rsqrtf(ss2 * (1.0f / 192.0f) + 1e-5f);
  ushort_t* obrow = outb + (size_t)grow * DD;
#pragma unroll
  for (int j = 0; j < 6; ++j) {
    ushort_t zb[4];
#pragma unroll
    for (int e = 0; e < 4; ++e) {
      int col = j * 32 + l8 * 4 + e;
      float z = vld ? (y[j*4+e] - mu2) * inv2 * g_f[col] + b_f[col] : y[j*4+e];
      zb[e] = f2bf(z);
    }
    *(uint2*)(obrow + j * 32 + l8 * 4) = *(const uint2*)(&zb[0]);
  }
}

// ---------------------------------------------------------------------------
// Fused FFN + final residual + LN. 256 threads (4 waves), 64 rows/block.
// ---------------------------------------------------------------------------
__global__ __launch_bounds__(256, 3) void ffn_fused_kernel(
    const ushort_t* __restrict__ A, const ushort_t* __restrict__ W1t,
    const float* __restrict__ bias1, const ushort_t* __restrict__ W2t,
    const float* __restrict__ bias2,
    const int* __restrict__ va, const int* __restrict__ vb,
    const float* __restrict__ g_f, const float* __restrict__ b_f,
    float* __restrict__ outf) {
  __shared__ float smemf[64 * 196];      // 50.2 KB epilogue Cs; overlays:
  ushort_t* As = (ushort_t*)smemf;       //   As 64*200 us (25.6 KB)
  ushort_t* Hs = As + 64 * 200;          //   Hs 2*64*72 us (18.4 KB)

  int tid = threadIdx.x;
  int w = tid >> 6;
  int lane = tid & 63;
  int l15 = lane & 15;
  int kq = lane >> 4;
  int row0 = blockIdx.x * 64;
  int side = row0 >= ROWS;
  int rb0 = row0 - side * ROWS;

  // stage A: 64 rows x 24 uint4 = 1536 / 256 threads = 6 each
#pragma unroll
  for (int i = 0; i < 6; ++i) {
    int idx = tid + i * 256;
    int r = idx / 24, c = (idx % 24) * 8;
    *(uint4*)(&As[r * 200 + c]) = *(const uint4*)(A + (size_t)(row0 + r) * DD + c);
  }

  const ushort_t* w1p = W1t + (size_t)(w * 16 + l15) * DD + kq * 8;
  const ushort_t* w2p = W2t + (size_t)(w * 48 + l15) * HID + kq * 8;

  U4BF8 w1f[6], w1n[6], w2f[6];
#pragma unroll
  for (int kk = 0; kk < 6; ++kk)
    w1f[kk].u = *(const uint4*)(w1p + kk * 32);  // hc = 0

  f32x4 Cacc[4][3];
#pragma unroll
  for (int qs = 0; qs < 4; ++qs)
#pragma unroll
    for (int nt = 0; nt < 3; ++nt) Cacc[qs][nt] = (f32x4){0.f, 0.f, 0.f, 0.f};

  __syncthreads();   // As ready

  for (int hc = 0; hc < 12; ++hc) {
#pragma unroll
    for (int kk2 = 0; kk2 < 2; ++kk2)
#pragma unroll
      for (int nt = 0; nt < 3; ++nt)
        w2f[kk2 * 3 + nt].u =
            *(const uint4*)(w2p + (size_t)(nt * 16) * HID + hc * 64 + kk2 * 32);

    f32x4 Hacc[4];
#pragma unroll
    for (int qs = 0; qs < 4; ++qs) Hacc[qs] = (f32x4){0.f, 0.f, 0.f, 0.f};
#pragma unroll
    for (int kk = 0; kk < 6; ++kk) {
#pragma unroll
      for (int qs = 0; qs < 4; ++qs) {
        bf16x8 af = *(const bf16x8*)(&As[(qs * 16 + l15) * 200 + kk * 32 + kq * 8]);
        Hacc[qs] = __builtin_amdgcn_mfma_f32_16x16x32_bf16(
            af, w1f[kk].b, Hacc[qs], 0, 0, 0);
      }
    }

    if (hc < 11) {
#pragma unroll
      for (int kk = 0; kk < 6; ++kk)
        w1n[kk].u = *(const uint4*)(w1p + (size_t)(hc + 1) * 64 * DD + kk * 32);
    }

    {
      float bb = bias1[hc * 64 + w * 16 + l15];
      ushort_t* hb = &Hs[(hc & 1) * 4608];
#pragma unroll
      for (int qs = 0; qs < 4; ++qs)
#pragma unroll
        for (int r = 0; r < 4; ++r) {
          float x = Hacc[qs][r] + bb;
          x = 0.5f * x * (1.0f + erff(x * 0.70710678118654752f));
          hb[(qs * 16 + kq * 4 + r) * 72 + w * 16 + l15] = f2bf(x);
        }
    }
    __syncthreads();

#pragma unroll
    for (int kk2 = 0; kk2 < 2; ++kk2) {
      bf16x8 hf[4];
#pragma unroll
      for (int qs = 0; qs < 4; ++qs)
        hf[qs] = *(const bf16x8*)(&Hs[(hc & 1) * 4608 +
                                      (qs * 16 + l15) * 72 + kk2 * 32 + kq * 8]);
#pragma unroll
      for (int nt = 0; nt < 3; ++nt)
#pragma unroll
        for (int qs = 0; qs < 4; ++qs)
          Cacc[qs][nt] = __builtin_amdgcn_mfma_f32_16x16x32_bf16(
              hf[qs], w2f[kk2 * 3 + nt].b, Cacc[qs][nt], 0, 0, 0);
    }

#pragma unroll
    for (int kk = 0; kk < 6; ++kk) w1f[kk] = w1n[kk];
  }
  __syncthreads();   // As/Hs dead; smemf becomes epilogue Cs

  // epilogue: stage C + bias2, then per-row residual + masked LN
  float* Cs = smemf;
#pragma unroll
  for (int qs = 0; qs < 4; ++qs)
#pragma unroll
    for (int nt = 0; nt < 3; ++nt) {
      int col = w * 48 + nt * 16 + l15;
      float bb = bias2[col];
#pragma unroll
      for (int r = 0; r < 4; ++r)
        Cs[(qs * 16 + kq * 4 + r) * 196 + col] = Cacc[qs][nt][r] + bb;
    }
  __syncthreads();

  // 4 threads/row, interleaved cols (col = j*16 + l4*4)
  int row = tid >> 2, l4 = tid & 3;
  int grow = row0 + row;
  float* orow = outf + (size_t)grow * DD;
  const float* crow = &Cs[row * 196];
  float v[48];
  float s = 0.f;
#pragma unroll
  for (int j = 0; j < 12; ++j) {
    int col = j * 16 + l4 * 4;
    float4 q = *(const float4*)(orow + col);   // residual (in-place read)
    v[j*4+0] = crow[col+0] + q.x; v[j*4+1] = crow[col+1] + q.y;
    v[j*4+2] = crow[col+2] + q.z; v[j*4+3] = crow[col+3] + q.w;
    s += v[j*4+0] + v[j*4+1] + v[j*4+2] + v[j*4+3];
  }
  s += __shfl_xor(s, 1); s += __shfl_xor(s, 2);
  float mu = s * (1.0f / 192.0f);
  float ss = 0.f;
#pragma unroll
  for (int j = 0; j < 48; ++j) { float d = v[j] - mu; ss += d * d; }
  ss += __shfl_xor(ss, 1); ss += __shfl_xor(ss, 2);
  float inv = rsqrtf(ss * (1.0f / 192.0f) + 1e-5f);
  int vld = (side ? vb : va)[rb0 + row];
#pragma unroll
  for (int j = 0; j < 12; ++j) {
    int col = j * 16 + l4 * 4;
    float4 q;
#pragma unroll
    for (int e = 0; e < 4; ++e) {
      float vv = v[j * 4 + e];
      ((float*)&q)[e] = vld ? (vv - mu) * inv * g_f[col + e] + b_f[col + e] : vv;
    }
    *(float4*)(orow + col) = q;
  }
}

// ---------------------------------------------------------------------------
// MFMA flash attention (best-measured R3 variant, 79.3us): dbuf V staging,
// K/V/valid prefetched one tile ahead, lean exp2 softmax, + s_setprio
// around both MFMA clusters (T5).
// ---------------------------------------------------------------------------
__global__ __launch_bounds__(256) void attn_mfma_kernel(
    const ushort_t* __restrict__ QKV,
    const int* __restrict__ valid_a, const int* __restrict__ valid_b,
    ushort_t* __restrict__ out) {
  int i = blockIdx.x;
  int gid = ((i >> 5) << 3) | (i & 7);
  int qt = (i >> 3) & 3;
  int side = gid >= BB * HH;
  int grem = side ? gid - BB * HH : gid;
  int h = grem % HH;
  int batch = grem / HH;
  int tid = threadIdx.x;
  int w = tid >> 6;
  int lane = tid & 63;
  int l15 = lane & 15;
  int kq = lane >> 4;

  const int* validq = side ? valid_b : valid_a;
  const int* validk = side ? valid_a : valid_b;
  size_t qrow0  = (size_t)side * ROWS + (size_t)batch * LL;
  size_t kvrow0 = (size_t)(1 - side) * ROWS + (size_t)batch * LL;

  __shared__ ushort_t VsT[2][32 * 72];
  __shared__ ushort_t Ps[4][32 * 72];

  int qbase = qt * 128 + w * 32;

  U4BF8 qfrag[2];
#pragma unroll
  for (int qs = 0; qs < 2; ++qs)
    qfrag[qs].u = *(const uint4*)(QKV + (qrow0 + qbase + qs * 16 + l15) * 576 +
                                  h * DKK + kq * 8);

  // per-(qs,r) fma coefficients: sqf = vq ? SB2 : 0, mq = vq ? 0 : -36
  float sqf[2][4], mq[2][4];
#pragma unroll
  for (int qs = 0; qs < 2; ++qs)
#pragma unroll
    for (int r = 0; r < 4; ++r) {
      int vq = validq[batch * LL + qbase + qs * 16 + kq * 4 + r];
      sqf[qs][r] = vq ? SB2 : 0.0f;
      mq[qs][r]  = vq ? 0.0f : MASKED_X;
    }

  float lsum[2][4];
  f32x4 Oacc[2][2];
#pragma unroll
  for (int qs = 0; qs < 2; ++qs) {
#pragma unroll
    for (int r = 0; r < 4; ++r) lsum[qs][r] = 0.0f;
#pragma unroll
    for (int ds = 0; ds < 2; ++ds) Oacc[qs][ds] = (f32x4){0.f, 0.f, 0.f, 0.f};
  }

  // prologue: load tile-0 V, K, valid
  uint4 vv = *(const uint4*)(QKV + (kvrow0 + lane) * 576 + 384 + h * DKK + w * 8);
  U4BF8 kf[4];
  int vki[4];
#pragma unroll
  for (int ks = 0; ks < 4; ++ks) {
    kf[ks].u = *(const uint4*)(QKV + (kvrow0 + ks * 16 + l15) * 576 +
                               192 + h * DKK + kq * 8);
    vki[ks] = validk[batch * LL + ks * 16 + l15];
  }

  for (int c = 0; c < LL; c += 64) {
    int buf = (c >> 6) & 1;
    // stage this tile's V (regs -> LDS), transposed to [d][k]
    {
      uint_t uu[4] = {vv.x, vv.y, vv.z, vv.w};
#pragma unroll
      for (int j = 0; j < 4; ++j) {
        VsT[buf][(w * 8 + 2 * j) * 72 + lane]     = (ushort_t)(uu[j] & 0xffffu);
        VsT[buf][(w * 8 + 2 * j + 1) * 72 + lane] = (ushort_t)(uu[j] >> 16);
      }
    }
    uint4 vvn;
    if (c + 64 < LL)
      vvn = *(const uint4*)(QKV + (kvrow0 + c + 64 + lane) * 576 +
                            384 + h * DKK + w * 8);
    __syncthreads();   // VsT[buf] ready (prev readers of buf are 2 tiles back)

    // S = Q K^T for this tile (K already in regs)
    f32x4 S[2][4];
    __builtin_amdgcn_s_setprio(1);
#pragma unroll
    for (int ks = 0; ks < 4; ++ks)
#pragma unroll
      for (int qs = 0; qs < 2; ++qs) {
        f32x4 z = (f32x4){0.f, 0.f, 0.f, 0.f};
        S[qs][ks] = __builtin_amdgcn_mfma_f32_16x16x32_bf16(
            qfrag[qs].b, kf[ks].b, z, 0, 0, 0);
      }
    __builtin_amdgcn_s_setprio(0);

    float mkb[4];
#pragma unroll
    for (int ks = 0; ks < 4; ++ks) mkb[ks] = vki[ks] ? 0.0f : MASKED_X;

    // prefetch next tile's K + valid (hidden under softmax+PV)
    U4BF8 kfn[4];
    int vkn[4];
    if (c + 64 < LL) {
#pragma unroll
      for (int ks = 0; ks < 4; ++ks) {
        kfn[ks].u = *(const uint4*)(QKV + (kvrow0 + c + 64 + ks * 16 + l15) * 576 +
                                    192 + h * DKK + kq * 8);
        vkn[ks] = validk[batch * LL + c + 64 + ks * 16 + l15];
      }
    }

    // softmax numerator: p = exp2(fma(S, sqf, min(mq, mkb)))
#pragma unroll
    for (int qs = 0; qs < 2; ++qs)
#pragma unroll
      for (int ks = 0; ks < 4; ++ks)
#pragma unroll
        for (int r = 0; r < 4; ++r) {
          float xs = fmaf(S[qs][ks][r], sqf[qs][r], fminf(mq[qs][r], mkb[ks]));
          float p = __builtin_amdgcn_exp2f(xs);
          lsum[qs][r] += p;
          Ps[w][(qs * 16 + kq * 4 + r) * 72 + ks * 16 + l15] = cvt_bf(p);
        }

    // PV
    __builtin_amdgcn_s_setprio(1);
#pragma unroll
    for (int kh = 0; kh < 2; ++kh) {
      bf16x8 pf[2], vf[2];
#pragma unroll
      for (int qs = 0; qs < 2; ++qs)
        pf[qs] = *(const bf16x8*)(&Ps[w][(qs * 16 + l15) * 72 + kh * 32 + kq * 8]);
#pragma unroll
      for (int ds = 0; ds < 2; ++ds)
        vf[ds] = *(const bf16x8*)(&VsT[buf][(ds * 16 + l15) * 72 + kh * 32 + kq * 8]);
#pragma unroll
      for (int qs = 0; qs < 2; ++qs)
#pragma unroll
        for (int ds = 0; ds < 2; ++ds)
          Oacc[qs][ds] = __builtin_amdgcn_mfma_f32_16x16x32_bf16(
              pf[qs], vf[ds], Oacc[qs][ds], 0, 0, 0);
    }
    __builtin_amdgcn_s_setprio(0);

    vv = vvn;
#pragma unroll
    for (int ks = 0; ks < 4; ++ks) { kf[ks] = kfn[ks]; vki[ks] = vkn[ks]; }
  }

#pragma unroll
  for (int qs = 0; qs < 2; ++qs)
#pragma unroll
    for (int r = 0; r < 4; ++r) {
      float sm = lsum[qs][r];
#pragma unroll
      for (int off = 1; off < 16; off <<= 1) sm += __shfl_xor(sm, off);
      lsum[qs][r] = sm;
    }

#pragma unroll
  for (int qs = 0; qs < 2; ++qs)
#pragma unroll
    for (int ds = 0; ds < 2; ++ds)
#pragma unroll
      for (int r = 0; r < 4; ++r) {
        int q = qbase + qs * 16 + kq * 4 + r;
        out[(qrow0 + q) * DD + h * DKK + ds * 16 + l15] =
            f2bf(Oacc[qs][ds][r] / lsum[qs][r]);
      }
}

// ---------------------------------------------------------------------------
extern "C" void kernel_launch(void* const* d_in, const int* in_sizes, int n_in,
                              void* d_out, int out_size, void* d_ws, size_t ws_size,
                              hipStream_t stream) {
  const float* x_a = (const float*)d_in[0];
  const float* x_b = (const float*)d_in[1];
  const int* valid_a = (const int*)d_in[2];
  const int* valid_b = (const int*)d_in[3];
  const float* ln_a_g = (const float*)d_in[4];
  const float* ln_a_b = (const float*)d_in[5];
  const float* ln_b_g = (const float*)d_in[6];
  const float* ln_b_b = (const float*)d_in[7];
  const float* ln_oa_g = (const float*)d_in[8];
  const float* ln_oa_b = (const float*)d_in[9];
  const float* ln_ob_g = (const float*)d_in[10];
  const float* ln_ob_b = (const float*)d_in[11];
  const float* wq = (const float*)d_in[12];
  const float* bq = (const float*)d_in[13];
  const float* wk = (const float*)d_in[14];
  const float* bk = (const float*)d_in[15];
  const float* wv = (const float*)d_in[16];
  const float* bv = (const float*)d_in[17];
  const float* wo = (const float*)d_in[18];
  const float* bo = (const float*)d_in[19];
  const float* fln_g = (const float*)d_in[20];
  const float* fln_b = (const float*)d_in[21];
  const float* flno_g = (const float*)d_in[22];
  const float* flno_b = (const float*)d_in[23];
  const float* w1 = (const float*)d_in[24];
  const float* b1 = (const float*)d_in[25];
  const float* w2 = (const float*)d_in[26];
  const float* b2 = (const float*)d_in[27];

  // Workspace: weights [0, 887040); lnFull/attO bf16 [2R,192] at 887040;
  // QKV bf16 [2R,576] at 19761408.
  char* wsb = (char*)d_ws;
  ushort_t* Wqkv = (ushort_t*)wsb;
  ushort_t* Wo_t = Wqkv + 110592;
  ushort_t* W1_t = Wo_t + 36864;
  ushort_t* W2_t = W1_t + 147456;
  float*    bqkv = (float*)(W2_t + 147456);
  ushort_t* lnFull = (ushort_t*)(wsb + 887040);
  ushort_t* attO   = lnFull;
  ushort_t* QKV = (ushort_t*)(wsb + 19761408);

  float* out_a = (float*)d_out;   // [2R,192] fp32 contiguous

  dim3 b256(256);
  dim3 gGemm(2 * ROWS / 32);                    // 1536 row-blocks
  dim3 gAttn(BB * HH * 4 * 2);                  // 2304
  dim3 gFFN(2 * ROWS / 64);                     // 768

  hipLaunchKernelGGL(pack_kernel, dim3(1731), b256, 0, stream,
                     wq, wk, wv, wo, w1, w2, bq, bk, bv,
                     Wqkv, Wo_t, W1_t, W2_t, bqkv);

  // 1+2. fused pre-LN + QKV projection, both sides
  hipLaunchKernelGGL(qkv_ln_kernel, gGemm, b256, 0, stream,
                     x_a, x_b, valid_a, valid_b,
                     ln_a_g, ln_a_b, ln_b_g, ln_b_b,
                     Wqkv, bqkv, QKV);

  // 3. attention, both sides (R3 best-measured variant + setprio)
  hipLaunchKernelGGL(attn_mfma_kernel, gAttn, b256, 0, stream,
                     QKV, valid_a, valid_b, attO);

  // 4+5+6. fused O-proj + residual-LN -> d_out, FFN pre-LN -> lnFull bf16
  hipLaunchKernelGGL(oproj_ln_kernel, gGemm, b256, 0, stream,
                     attO, Wo_t, bo, x_a, x_b, valid_a, valid_b,
                     ln_oa_g, ln_oa_b, ln_ob_g, ln_ob_b, fln_g, fln_b,
                     out_a, lnFull);

  // 7+8. fused FFN + final residual + LN -> d_out (in place)
  hipLaunchKernelGGL(ffn_fused_kernel, gFFN, b256, 0, stream,
                     lnFull, W1_t, b1, W2_t, b2, valid_a, valid_b,
                     flno_g, flno_b, out_a);
}